// Round 5
// baseline (1025.515 us; speedup 1.0000x reference)
//
#include <hip/hip_runtime.h>
#include <stdint.h>

#define N      8192
#define FEAT   512
#define HID    64
#define NH     4
#define C1     256          // NH*HID
#define PCH    65           // accA per-head stride (64 data + Z at col 64)
#define TC     260          // NH*PCH
#define NCLS   16
#define C2     32           // accB stride (16 data + Z at col 16)
#define IPB    8            // rows per block in k1
#define LOG2E  1.44269504f

typedef __attribute__((ext_vector_type(8))) short bf16x8;
typedef __attribute__((ext_vector_type(4))) float f32x4;

__device__ __forceinline__ float b2f(uint16_t u){
  uint32_t x = ((uint32_t)u) << 16;
  return __builtin_bit_cast(float, x);
}
__device__ __forceinline__ uint16_t f2b(float f){
  uint32_t x = __builtin_bit_cast(uint32_t, f);
  uint32_t r = (x + 0x7fffu + ((x >> 16) & 1u)) >> 16;
  return (uint16_t)r;
}
__device__ __forceinline__ float lrelu(float v, float a){ return fmaxf(v, a * v); }
__device__ __forceinline__ float fexp2(float x){
#if __has_builtin(__builtin_amdgcn_exp2f)
  return __builtin_amdgcn_exp2f(x);
#else
  return exp2f(x);
#endif
}
__device__ __forceinline__ uint32_t pk_bf16(float lo, float hi){
  uint32_t r;
  asm("v_cvt_pk_bf16_f32 %0, %1, %2" : "=v"(r) : "v"(lo), "v"(hi));
  return r;
}

// build one A-fragment (8 scores) fully in registers; masked by 8 adjacency bits
__device__ __forceinline__ bf16x8 mk_frag(float f1v, float4 fa, float4 fb,
                                          uint32_t ub, float& dsum){
  float e0, e1, e2, e3, e4, e5, e6, e7, s;
  s = f1v + fa.x; e0 = fexp2(fmaxf(s, 0.2f * s)); if (!(ub &   1u)) e0 = 0.f;
  s = f1v + fa.y; e1 = fexp2(fmaxf(s, 0.2f * s)); if (!(ub &   2u)) e1 = 0.f;
  s = f1v + fa.z; e2 = fexp2(fmaxf(s, 0.2f * s)); if (!(ub &   4u)) e2 = 0.f;
  s = f1v + fa.w; e3 = fexp2(fmaxf(s, 0.2f * s)); if (!(ub &   8u)) e3 = 0.f;
  s = f1v + fb.x; e4 = fexp2(fmaxf(s, 0.2f * s)); if (!(ub &  16u)) e4 = 0.f;
  s = f1v + fb.y; e5 = fexp2(fmaxf(s, 0.2f * s)); if (!(ub &  32u)) e5 = 0.f;
  s = f1v + fb.z; e6 = fexp2(fmaxf(s, 0.2f * s)); if (!(ub &  64u)) e6 = 0.f;
  s = f1v + fb.w; e7 = fexp2(fmaxf(s, 0.2f * s)); if (!(ub & 128u)) e7 = 0.f;
  dsum += ((e0 + e1) + (e2 + e3)) + ((e4 + e5) + (e6 + e7));
  union { uint32_t u[4]; bf16x8 v; } r;
  r.u[0] = pk_bf16(e0, e1);
  r.u[1] = pk_bf16(e2, e3);
  r.u[2] = pk_bf16(e4, e5);
  r.u[3] = pk_bf16(e6, e7);
  return r.v;
}

#define MFMA16(a, b, c) __builtin_amdgcn_mfma_f32_16x16x32_bf16((a), (b), (c), 0, 0, 0)

// ---------------------------------------------------------------- kp: adj -> transposed bitmask adjT[w32][row]
__global__ __launch_bounds__(256) void kp_pack(const int* __restrict__ adj,
                                               uint32_t* __restrict__ adjT){
  __shared__ uint32_t tile[64][129];
  int t = threadIdx.x, lane = t & 63, wv = t >> 6;
  int jh = blockIdx.x & 1;            // half of j-range
  int i0 = (blockIdx.x >> 1) * 64;    // 64-row set
  const int jbase = jh * 4096;
  for (int r = 0; r < 16; ++r){
    int row = wv * 16 + r;
    const int* arow = adj + (size_t)(i0 + row) * N + jbase;
    for (int g = 0; g < 64; ++g){
      unsigned long long mb = __ballot(arow[g * 64 + lane] > 0);
      if (lane == 0){
        tile[row][2 * g]     = (uint32_t)mb;
        tile[row][2 * g + 1] = (uint32_t)(mb >> 32);
      }
    }
  }
  __syncthreads();
  // coalesced store: lanes sweep rows for fixed word
  #pragma unroll
  for (int chunk = 0; chunk < 32; ++chunk){
    int wloc = wv * 32 + chunk;               // 0..127
    int w32 = jh * 128 + wloc;
    adjT[(size_t)w32 * N + i0 + lane] = tile[lane][wloc];
  }
}

// ---------------------------------------------------------------- k1: H = x @ Wh (scalar-x, coalesced W, no LDS)
__global__ __launch_bounds__(256) void k1_h(const float* __restrict__ x,
    const float* __restrict__ Wh, const float* __restrict__ ah,
    uint16_t* __restrict__ H, float* __restrict__ f1, float* __restrict__ f2)
{
  int t = threadIdx.x;
  int i0 = blockIdx.x * IPB;
  int k = t >> 6, cc = t & 63;
  const float* wcol = Wh + k * 32768 + cc;    // [k][f][cc], stride 64 over f
  float acc[IPB] = {};
  for (int f = 0; f < FEAT; f += 4){
    float w0 = wcol[(f + 0) * 64];
    float w1 = wcol[(f + 1) * 64];
    float w2 = wcol[(f + 2) * 64];
    float w3 = wcol[(f + 3) * 64];
    #pragma unroll
    for (int ii = 0; ii < IPB; ++ii){
      const float* xr = x + (size_t)(i0 + ii) * FEAT + f;   // wave-uniform -> s_load
      acc[ii] += xr[0] * w0 + xr[1] * w1 + xr[2] * w2 + xr[3] * w3;
    }
  }
  float a1 = ah[k * 128 + cc], a2 = ah[k * 128 + 64 + cc];
  #pragma unroll
  for (int ii = 0; ii < IPB; ++ii){
    int i = i0 + ii;
    H[(size_t)i * C1 + t] = f2b(acc[ii]);
    float c1v = acc[ii] * a1, c2v = acc[ii] * a2;
    #pragma unroll
    for (int off = 32; off; off >>= 1){
      c1v += __shfl_down(c1v, off);
      c2v += __shfl_down(c2v, off);
    }
    if (cc == 0){ f1[k * N + i] = c1v * LOG2E; f2[k * N + i] = c2v * LOG2E; }
  }
}

// ---------------------------------------------------------------- k2a: H -> fragment-packed Bp[head][jcg][ct][lane][8]
__global__ void k2a_pack(const uint16_t* __restrict__ H, uint16_t* __restrict__ Bp){
  __shared__ uint16_t tile[64][72];
  int bid = blockIdx.x;               // 128 i-tiles x 4 heads
  int k = bid & 3, it = bid >> 2;
  int i0 = it * 64;
  int t = threadIdx.x;
  #pragma unroll
  for (int r = 0; r < 4; ++r){
    int ii = r * 16 + (t >> 4);
    int pp = (t & 15) * 4;
    uint2 v = *(const uint2*)(H + (size_t)(i0 + ii) * C1 + k * 64 + pp);
    const uint16_t* s = (const uint16_t*)&v;
    tile[pp + 0][ii] = s[0]; tile[pp + 1][ii] = s[1];
    tile[pp + 2][ii] = s[2]; tile[pp + 3][ii] = s[3];
  }
  __syncthreads();
  #pragma unroll
  for (int r = 0; r < 2; ++r){
    int jl = r;
    int ct = t >> 6;
    int lane = t & 63;
    int m = lane & 15, q = lane >> 4;
    uint4 v = *(const uint4*)&tile[ct * 16 + m][jl * 32 + q * 8];
    size_t off = ((((size_t)k * 256 + (i0 >> 5) + jl) * 4 + ct) * 64 + lane) * 8;
    *(uint4*)(Bp + off) = v;
  }
}

// ---------------------------------------------------------------- k3: phase-A attention — depth-2 B prefetch, adjT
#define K3_LOADB(BD, JC)                                                        \
  { const int jb = (JC) & 63;                                                   \
    _Pragma("unroll")                                                           \
    for (int ct = 0; ct < 4; ++ct)                                              \
      BD[ct] = *(const bf16x8*)(bpbase + (size_t)(jb * 4 + ct) * 512); }

#define K3_LOADWF(W0d, W1d, F0d, F1d, JC)                                       \
  { const int jw = (JC) & 63;                                                   \
    W0d = adjT[awbase + (size_t)jw * N];                                        \
    W1d = adjT[awbase + (size_t)jw * N + 16];                                   \
    F0d = *(const float4*)(f2js + jw * 32 + 8 * q);                             \
    F1d = *(const float4*)(f2js + jw * 32 + 8 * q + 4); }

#define K3_COMP(BU, W0u, W1u, F0u, F1u)                                         \
  { bf16x8 af0 = mk_frag(f1v0, F0u, F1u, (W0u >> (8 * q)) & 255u, dsum0);       \
    bf16x8 af1 = mk_frag(f1v1, F0u, F1u, (W1u >> (8 * q)) & 255u, dsum1);       \
    _Pragma("unroll")                                                           \
    for (int ct = 0; ct < 4; ++ct){                                             \
      acc[0][ct] = MFMA16(af0, BU[ct], acc[0][ct]);                             \
      acc[1][ct] = MFMA16(af1, BU[ct], acc[1][ct]);                             \
    } }

#define K3_STEP(BU, BL, JB, U, L, JW)                                           \
  { K3_LOADB(BL, JB);                                                           \
    K3_LOADWF(w##L##0, w##L##1, f##L##0, f##L##1, JW);                          \
    K3_COMP(BU, w##U##0, w##U##1, f##U##0, f##U##1) }

__global__ __launch_bounds__(256, 4) void k3_attA(const uint32_t* __restrict__ adjT,
    const uint16_t* __restrict__ Bp, const float* __restrict__ f1,
    const float* __restrict__ f2, float* __restrict__ accA)
{
  const int t = threadIdx.x;
  const int ibl = blockIdx.x & 255;   // 256 i-tiles of 32 rows
  const int js  = blockIdx.x >> 8;    // 0..3
  const int gi0 = ibl * 32;

  const int lane = t & 63;
  const int head = t >> 6;            // wave = head
  const int m    = lane & 15;
  const int q    = lane >> 4;

  const int row0  = gi0 + m;
  const float* f2js = f2 + (size_t)head * N + js * 2048;
  const float f1v0 = f1[(size_t)head * N + row0];
  const float f1v1 = f1[(size_t)head * N + row0 + 16];
  const uint16_t* bpbase = Bp + (((size_t)head * 256 + js * 64) * 4) * 512 + lane * 8;
  const size_t awbase = (size_t)(js * 64) * N + row0;   // adjT[js*64 + jw][row0(+16)]

  f32x4 acc[2][4] = {};
  float dsum0 = 0.f, dsum1 = 0.f;

  bf16x8 b0[4], b1[4], b2[4];
  uint32_t wA0, wA1, wB0, wB1;
  float4 fA0, fA1, fB0, fB1;

  // prologue: B(0), B(1), WF(0)
  K3_LOADB(b0, 0)
  K3_LOADB(b1, 1)
  K3_LOADWF(wA0, wA1, fA0, fA1, 0)

  for (int i = 0; i < 10; ++i){
    const int kb = i * 6;
    K3_STEP(b0, b2, kb + 2, A, B, kb + 1)
    K3_STEP(b1, b0, kb + 3, B, A, kb + 2)
    K3_STEP(b2, b1, kb + 4, A, B, kb + 3)
    K3_STEP(b0, b2, kb + 5, B, A, kb + 4)
    K3_STEP(b1, b0, kb + 6, A, B, kb + 5)
    K3_STEP(b2, b1, kb + 7, B, A, kb + 6)
  }
  // epilogue: bodies 60..63 (wrapped loads are harmless)
  K3_STEP(b0, b2, 62, A, B, 61)
  K3_STEP(b1, b0, 63, B, A, 62)
  K3_STEP(b2, b1, 64, A, B, 63)
  K3_STEP(b0, b2, 65, B, A, 64)

  #pragma unroll
  for (int itl = 0; itl < 2; ++itl)
    #pragma unroll
    for (int ct = 0; ct < 4; ++ct)
      #pragma unroll
      for (int reg = 0; reg < 4; ++reg){
        int gi = gi0 + itl * 16 + q * 4 + reg;
        accA[((size_t)js * N + gi) * TC + head * PCH + ct * 16 + m] = acc[itl][ct][reg];
      }
  {
    float v0 = dsum0, v1 = dsum1;
    v0 += __shfl_xor(v0, 16); v0 += __shfl_xor(v0, 32);
    v1 += __shfl_xor(v1, 16); v1 += __shfl_xor(v1, 32);
    if (q == 0){
      accA[((size_t)js * N + row0)      * TC + head * PCH + 64] = v0;
      accA[((size_t)js * N + row0 + 16) * TC + head * PCH + 64] = v1;
    }
  }
}

// ---------------------------------------------------------------- k4: reduce partials -> xcat (lrelu 0.01)
__global__ void k4_redA(const float* __restrict__ accA, uint16_t* __restrict__ xcat){
  int i = blockIdx.x;
  int t = threadIdx.x;
  int k = t >> 6, cc = t & 63;
  size_t base = (size_t)i * TC + k * PCH;
  float v = 0.f, Z = 0.f;
  #pragma unroll
  for (int js = 0; js < 4; ++js){
    const float* p = accA + (size_t)js * N * TC + base;
    v += p[cc];
    Z += p[64];
  }
  float r = v / Z;
  xcat[(size_t)i * C1 + t] = f2b(lrelu(r, 0.01f));
}

// ---------------------------------------------------------------- k5: h2 = xcat@Wo, f1o/f2o (scaled), packed Bp2
__global__ __launch_bounds__(256) void k5_h2(const uint16_t* __restrict__ xcat,
    const float* __restrict__ Wo, const float* __restrict__ ao,
    uint16_t* __restrict__ Bp2, float* __restrict__ f1o, float* __restrict__ f2o)
{
  __shared__ uint16_t xs[16][256];
  __shared__ uint16_t hs[16][16];
  int t = threadIdx.x;
  int i0 = blockIdx.x * 16;
  #pragma unroll
  for (int r = 0; r < 2; ++r){
    int idx = t + 256 * r;
    int ii = idx >> 5, o4 = idx & 31;
    *(uint4*)&xs[ii][o4 * 8] = *(const uint4*)(xcat + (size_t)(i0 + ii) * C1 + o4 * 8);
  }
  __syncthreads();
  int ii = t >> 4, c = t & 15;
  float acc = 0.f;
  for (int f = 0; f < 256; ++f)
    acc += b2f(xs[ii][f]) * Wo[f * 16 + c];
  int i = i0 + ii;
  hs[ii][c] = f2b(acc);
  float u1 = acc * ao[c];
  float u2 = acc * ao[16 + c];
  #pragma unroll
  for (int off = 8; off; off >>= 1){
    u1 += __shfl_down(u1, off, 16);
    u2 += __shfl_down(u2, off, 16);
  }
  if (c == 0){ f1o[i] = u1 * LOG2E; f2o[i] = u2 * LOG2E; }
  __syncthreads();
  if (t < 32){
    int q_l = t >> 4, mm = t & 15;
    uint16_t tmp[8];
    #pragma unroll
    for (int s = 0; s < 8; ++s) tmp[s] = hs[8 * q_l + s][mm];
    int jcg = i0 >> 5, half = (i0 >> 4) & 1;
    size_t off = ((size_t)jcg * 64 + (2 * half + q_l) * 16 + mm) * 8;
    *(uint4*)(Bp2 + off) = *(uint4*)tmp;
  }
}

// ---------------------------------------------------------------- k6: phase-B attention — barrier-free, adjT, packed-B
#define K6_BODY(JC, CUR, NXT)                                                   \
  {                                                                             \
    const int jcn = ((JC) + 1) & 31;                                            \
    b##NXT = *(const bf16x8*)(bp2 + (size_t)jcn * 512);                         \
    w##NXT = adjT[(size_t)(js * 32 + jcn) * N + row];                           \
    f##NXT##0 = *(const float4*)(f2o + js * 1024 + jcn * 32 + 8 * q);           \
    f##NXT##1 = *(const float4*)(f2o + js * 1024 + jcn * 32 + 8 * q + 4);       \
    bf16x8 af = mk_frag(f1v, f##CUR##0, f##CUR##1,                              \
                        (w##CUR >> (8 * q)) & 255u, dsum);                      \
    acc0 = MFMA16(af, b##CUR, acc0);                                            \
  }

__global__ __launch_bounds__(256, 4) void k6_attB(const uint32_t* __restrict__ adjT,
    const uint16_t* __restrict__ Bp2, const float* __restrict__ f1o,
    const float* __restrict__ f2o, float* __restrict__ accB)
{
  const int t = threadIdx.x;
  const int ibl = blockIdx.x & 127;   // 128 i-tiles of 64 rows
  const int js  = blockIdx.x >> 7;    // 0..7
  const int gi0 = ibl * 64;

  const int lane = t & 63;
  const int w = t >> 6;               // wave 0..3
  const int m = lane & 15;
  const int q = lane >> 4;

  const int row = gi0 + w * 16 + m;
  const float f1v = f1o[row];
  const uint16_t* bp2 = Bp2 + ((size_t)js * 32 * 64) * 8 + lane * 8;

  f32x4 acc0 = {0.f, 0.f, 0.f, 0.f};
  float dsum = 0.f;

  bf16x8 bA, bB;
  uint32_t wA, wB;
  float4 fA0, fA1, fB0, fB1;

  {   // prologue: jc = 0
    bA = *(const bf16x8*)(bp2);
    wA = adjT[(size_t)(js * 32) * N + row];
    fA0 = *(const float4*)(f2o + js * 1024 + 8 * q);
    fA1 = *(const float4*)(f2o + js * 1024 + 8 * q + 4);
  }

  for (int jc = 0; jc < 32; jc += 2){
    K6_BODY(jc,     A, B)
    K6_BODY(jc + 1, B, A)
  }

  #pragma unroll
  for (int reg = 0; reg < 4; ++reg){
    int gi = gi0 + w * 16 + q * 4 + reg;
    accB[((size_t)js * N + gi) * C2 + m] = acc0[reg];
  }
  {
    float v = dsum;
    v += __shfl_xor(v, 16); v += __shfl_xor(v, 32);
    if (q == 0)
      accB[((size_t)js * N + row) * C2 + 16] = v;
  }
}

// ---------------------------------------------------------------- k7: reduce -> out (fp32)
__global__ void k7_redB(const float* __restrict__ accB, float* __restrict__ out){
  int idx = blockIdx.x * 256 + threadIdx.x;   // 131072
  int i = idx >> 4, c = idx & 15;
  float v = 0.f, Z = 0.f;
  #pragma unroll
  for (int js = 0; js < 8; ++js){
    const float* p = accB + ((size_t)js * N + i) * C2;
    v += p[c];
    Z += p[16];
  }
  out[idx] = v / Z;
}

// ================================================================ launch
extern "C" void kernel_launch(void* const* d_in, const int* in_sizes, int n_in,
                              void* d_out, int out_size, void* d_ws, size_t ws_size,
                              hipStream_t stream)
{
  const float* x   = (const float*)d_in[0];
  const int*   adj = (const int*)d_in[1];
  const float* Wh  = (const float*)d_in[2];
  const float* ah  = (const float*)d_in[3];
  const float* Wo  = (const float*)d_in[4];
  const float* ao  = (const float*)d_in[5];
  float* out = (float*)d_out;

  char* ws = (char*)d_ws;
  uint16_t* H    = (uint16_t*)(ws);                 // 4 MB    [8192][256] bf16
  uint16_t* Bp   = (uint16_t*)(ws + 4194304);       // 4 MB    packed B-fragments phase A
  float*    f1   = (float*)   (ws + 8388608);       // 128 KB  (pre-scaled by log2e)
  float*    f2   = (float*)   (ws + 8519680);       // 128 KB
  float*    accA = (float*)   (ws + 8650752);       // 34.08 MB [4][8192][260]
  uint16_t* xcat = (uint16_t*)(ws + 42729472);      // 4 MB    [8192][256] bf16
  uint16_t* Bp2  = (uint16_t*)(ws + 46923776);      // 256 KB  packed B-fragments phase B
  float*    f1o  = (float*)   (ws + 47185920);      // 32 KB
  float*    f2o  = (float*)   (ws + 47218688);      // 32 KB
  float*    accB = (float*)   (ws + 47251456);      // 8 MB    [8][8192][32]
  uint32_t* adjT = (uint32_t*)(ws + 55640064);      // 8 MB    transposed bitmask [256][8192] (end 64028672)

  hipLaunchKernelGGL(kp_pack,  dim3(256),  dim3(256), 0, stream, adj, adjT);
  hipLaunchKernelGGL(k1_h,     dim3(1024), dim3(256), 0, stream, x, Wh, ah, H, f1, f2);
  hipLaunchKernelGGL(k2a_pack, dim3(512),  dim3(256), 0, stream, H, Bp);
  hipLaunchKernelGGL(k3_attA,  dim3(1024), dim3(256), 0, stream, adjT, Bp, f1, f2, accA);
  hipLaunchKernelGGL(k4_redA,  dim3(8192), dim3(256), 0, stream, accA, xcat);
  hipLaunchKernelGGL(k5_h2,    dim3(512),  dim3(256), 0, stream, xcat, Wo, ao, Bp2, f1o, f2o);
  hipLaunchKernelGGL(k6_attB,  dim3(1024), dim3(256), 0, stream, adjT, Bp2, f1o, f2o, accB);
  hipLaunchKernelGGL(k7_redB,  dim3(512),  dim3(256), 0, stream, accB, out);
}

// Round 6
// 693.506 us; speedup vs baseline: 1.4787x; 1.4787x over previous
//
#include <hip/hip_runtime.h>
#include <stdint.h>

#define N      8192
#define FEAT   512
#define HID    64
#define NH     4
#define C1     256          // NH*HID
#define PCH    65           // accA per-head stride (64 data + Z at col 64)
#define TC     260          // NH*PCH
#define NCLS   16
#define C2     32           // accB stride (16 data + Z at col 16)
#define IPB    8            // rows per block in k1
#define LOG2E  1.44269504f

typedef __attribute__((ext_vector_type(8))) short bf16x8;
typedef __attribute__((ext_vector_type(4))) float f32x4;

__device__ __forceinline__ float b2f(uint16_t u){
  uint32_t x = ((uint32_t)u) << 16;
  return __builtin_bit_cast(float, x);
}
__device__ __forceinline__ uint16_t f2b(float f){
  uint32_t x = __builtin_bit_cast(uint32_t, f);
  uint32_t r = (x + 0x7fffu + ((x >> 16) & 1u)) >> 16;
  return (uint16_t)r;
}
__device__ __forceinline__ float lrelu(float v, float a){ return fmaxf(v, a * v); }
__device__ __forceinline__ float fexp2(float x){
#if __has_builtin(__builtin_amdgcn_exp2f)
  return __builtin_amdgcn_exp2f(x);
#else
  return exp2f(x);
#endif
}
__device__ __forceinline__ uint32_t pk_bf16(float lo, float hi){
  uint32_t r;
  asm("v_cvt_pk_bf16_f32 %0, %1, %2" : "=v"(r) : "v"(lo), "v"(hi));
  return r;
}

// build one A-fragment (8 scores) fully in registers; masked by 8 adjacency bits
__device__ __forceinline__ bf16x8 mk_frag(float f1v, float4 fa, float4 fb,
                                          uint32_t ub, float& dsum){
  float e0, e1, e2, e3, e4, e5, e6, e7, s;
  s = f1v + fa.x; e0 = fexp2(fmaxf(s, 0.2f * s)); if (!(ub &   1u)) e0 = 0.f;
  s = f1v + fa.y; e1 = fexp2(fmaxf(s, 0.2f * s)); if (!(ub &   2u)) e1 = 0.f;
  s = f1v + fa.z; e2 = fexp2(fmaxf(s, 0.2f * s)); if (!(ub &   4u)) e2 = 0.f;
  s = f1v + fa.w; e3 = fexp2(fmaxf(s, 0.2f * s)); if (!(ub &   8u)) e3 = 0.f;
  s = f1v + fb.x; e4 = fexp2(fmaxf(s, 0.2f * s)); if (!(ub &  16u)) e4 = 0.f;
  s = f1v + fb.y; e5 = fexp2(fmaxf(s, 0.2f * s)); if (!(ub &  32u)) e5 = 0.f;
  s = f1v + fb.z; e6 = fexp2(fmaxf(s, 0.2f * s)); if (!(ub &  64u)) e6 = 0.f;
  s = f1v + fb.w; e7 = fexp2(fmaxf(s, 0.2f * s)); if (!(ub & 128u)) e7 = 0.f;
  dsum += ((e0 + e1) + (e2 + e3)) + ((e4 + e5) + (e6 + e7));
  union { uint32_t u[4]; bf16x8 v; } r;
  r.u[0] = pk_bf16(e0, e1);
  r.u[1] = pk_bf16(e2, e3);
  r.u[2] = pk_bf16(e4, e5);
  r.u[3] = pk_bf16(e6, e7);
  return r.v;
}

#define MFMA16(a, b, c) __builtin_amdgcn_mfma_f32_16x16x32_bf16((a), (b), (c), 0, 0, 0)

// ---------------------------------------------------------------- kp: adj -> transposed bitmask adjT[w32][row]
// one 64x64 tile per block; 16384 blocks -> HBM-bound (~41 us floor)
__global__ __launch_bounds__(256) void kp_pack(const int* __restrict__ adj,
                                               uint32_t* __restrict__ adjT){
  __shared__ uint32_t tile[2][64];
  int t = threadIdx.x, lane = t & 63, wv = t >> 6;
  int jt = blockIdx.x & 127;           // j-tile (64 cols)
  int i0 = (blockIdx.x >> 7) * 64;     // i-tile (64 rows)
  const int j0 = jt * 64;
  #pragma unroll
  for (int r = 0; r < 16; ++r){
    int row = wv * 16 + r;
    unsigned long long mb = __ballot(adj[(size_t)(i0 + row) * N + j0 + lane] > 0);
    if (lane == 0){
      tile[0][row] = (uint32_t)mb;
      tile[1][row] = (uint32_t)(mb >> 32);
    }
  }
  __syncthreads();
  if (t < 128){
    int ww = t >> 6, r = t & 63;
    adjT[(size_t)(jt * 2 + ww) * N + i0 + r] = tile[ww][r];
  }
}

// ---------------------------------------------------------------- k1: H = x @ Wh (scalar-x, coalesced W, no LDS)
__global__ __launch_bounds__(256) void k1_h(const float* __restrict__ x,
    const float* __restrict__ Wh, const float* __restrict__ ah,
    uint16_t* __restrict__ H, float* __restrict__ f1, float* __restrict__ f2)
{
  int t = threadIdx.x;
  int i0 = blockIdx.x * IPB;
  int k = t >> 6, cc = t & 63;
  const float* wcol = Wh + k * 32768 + cc;    // [k][f][cc], stride 64 over f
  float acc[IPB] = {};
  for (int f = 0; f < FEAT; f += 4){
    float w0 = wcol[(f + 0) * 64];
    float w1 = wcol[(f + 1) * 64];
    float w2 = wcol[(f + 2) * 64];
    float w3 = wcol[(f + 3) * 64];
    #pragma unroll
    for (int ii = 0; ii < IPB; ++ii){
      const float* xr = x + (size_t)(i0 + ii) * FEAT + f;   // wave-uniform -> s_load
      acc[ii] += xr[0] * w0 + xr[1] * w1 + xr[2] * w2 + xr[3] * w3;
    }
  }
  float a1 = ah[k * 128 + cc], a2 = ah[k * 128 + 64 + cc];
  #pragma unroll
  for (int ii = 0; ii < IPB; ++ii){
    int i = i0 + ii;
    H[(size_t)i * C1 + t] = f2b(acc[ii]);
    float c1v = acc[ii] * a1, c2v = acc[ii] * a2;
    #pragma unroll
    for (int off = 32; off; off >>= 1){
      c1v += __shfl_down(c1v, off);
      c2v += __shfl_down(c2v, off);
    }
    if (cc == 0){ f1[k * N + i] = c1v * LOG2E; f2[k * N + i] = c2v * LOG2E; }
  }
}

// ---------------------------------------------------------------- k2a: H -> fragment-packed Bp[head][jcg][ct][lane][8]
__global__ void k2a_pack(const uint16_t* __restrict__ H, uint16_t* __restrict__ Bp){
  __shared__ uint16_t tile[64][72];
  int bid = blockIdx.x;               // 128 i-tiles x 4 heads
  int k = bid & 3, it = bid >> 2;
  int i0 = it * 64;
  int t = threadIdx.x;
  #pragma unroll
  for (int r = 0; r < 4; ++r){
    int ii = r * 16 + (t >> 4);
    int pp = (t & 15) * 4;
    uint2 v = *(const uint2*)(H + (size_t)(i0 + ii) * C1 + k * 64 + pp);
    const uint16_t* s = (const uint16_t*)&v;
    tile[pp + 0][ii] = s[0]; tile[pp + 1][ii] = s[1];
    tile[pp + 2][ii] = s[2]; tile[pp + 3][ii] = s[3];
  }
  __syncthreads();
  #pragma unroll
  for (int r = 0; r < 2; ++r){
    int jl = r;
    int ct = t >> 6;
    int lane = t & 63;
    int m = lane & 15, q = lane >> 4;
    uint4 v = *(const uint4*)&tile[ct * 16 + m][jl * 32 + q * 8];
    size_t off = ((((size_t)k * 256 + (i0 >> 5) + jl) * 4 + ct) * 64 + lane) * 8;
    *(uint4*)(Bp + off) = v;
  }
}

// ---------------------------------------------------------------- k3: phase-A attention — depth-2 B prefetch, adjT
#define K3_LOADB(BD, JC)                                                        \
  { const int jb = (JC) & 63;                                                   \
    _Pragma("unroll")                                                           \
    for (int ct = 0; ct < 4; ++ct)                                              \
      BD[ct] = *(const bf16x8*)(bpbase + (size_t)(jb * 4 + ct) * 512); }

#define K3_LOADWF(W0d, W1d, F0d, F1d, JC)                                       \
  { const int jw = (JC) & 63;                                                   \
    W0d = adjT[awbase + (size_t)jw * N];                                        \
    W1d = adjT[awbase + (size_t)jw * N + 16];                                   \
    F0d = *(const float4*)(f2js + jw * 32 + 8 * q);                             \
    F1d = *(const float4*)(f2js + jw * 32 + 8 * q + 4); }

#define K3_COMP(BU, W0u, W1u, F0u, F1u)                                         \
  { bf16x8 af0 = mk_frag(f1v0, F0u, F1u, (W0u >> (8 * q)) & 255u, dsum0);       \
    bf16x8 af1 = mk_frag(f1v1, F0u, F1u, (W1u >> (8 * q)) & 255u, dsum1);       \
    _Pragma("unroll")                                                           \
    for (int ct = 0; ct < 4; ++ct){                                             \
      acc[0][ct] = MFMA16(af0, BU[ct], acc[0][ct]);                             \
      acc[1][ct] = MFMA16(af1, BU[ct], acc[1][ct]);                             \
    } }

#define K3_STEP(BU, BL, JB, U, L, JW)                                           \
  { K3_LOADB(BL, JB);                                                           \
    K3_LOADWF(w##L##0, w##L##1, f##L##0, f##L##1, JW);                          \
    K3_COMP(BU, w##U##0, w##U##1, f##U##0, f##U##1) }

__global__ __launch_bounds__(256, 4) void k3_attA(const uint32_t* __restrict__ adjT,
    const uint16_t* __restrict__ Bp, const float* __restrict__ f1,
    const float* __restrict__ f2, float* __restrict__ accA)
{
  const int t = threadIdx.x;
  const int ibl = blockIdx.x & 255;   // 256 i-tiles of 32 rows
  const int js  = blockIdx.x >> 8;    // 0..3
  const int gi0 = ibl * 32;

  const int lane = t & 63;
  const int head = t >> 6;            // wave = head
  const int m    = lane & 15;
  const int q    = lane >> 4;

  const int row0  = gi0 + m;
  const float* f2js = f2 + (size_t)head * N + js * 2048;
  const float f1v0 = f1[(size_t)head * N + row0];
  const float f1v1 = f1[(size_t)head * N + row0 + 16];
  const uint16_t* bpbase = Bp + (((size_t)head * 256 + js * 64) * 4) * 512 + lane * 8;
  const size_t awbase = (size_t)(js * 64) * N + row0;   // adjT[js*64 + jw][row0(+16)]

  f32x4 acc[2][4] = {};
  float dsum0 = 0.f, dsum1 = 0.f;

  bf16x8 b0[4], b1[4], b2[4];
  uint32_t wA0, wA1, wB0, wB1;
  float4 fA0, fA1, fB0, fB1;

  // prologue: B(0), B(1), WF(0)
  K3_LOADB(b0, 0)
  K3_LOADB(b1, 1)
  K3_LOADWF(wA0, wA1, fA0, fA1, 0)

  for (int i = 0; i < 10; ++i){
    const int kb = i * 6;
    K3_STEP(b0, b2, kb + 2, A, B, kb + 1)
    K3_STEP(b1, b0, kb + 3, B, A, kb + 2)
    K3_STEP(b2, b1, kb + 4, A, B, kb + 3)
    K3_STEP(b0, b2, kb + 5, B, A, kb + 4)
    K3_STEP(b1, b0, kb + 6, A, B, kb + 5)
    K3_STEP(b2, b1, kb + 7, B, A, kb + 6)
  }
  // epilogue: bodies 60..63 (wrapped loads are harmless)
  K3_STEP(b0, b2, 62, A, B, 61)
  K3_STEP(b1, b0, 63, B, A, 62)
  K3_STEP(b2, b1, 64, A, B, 63)
  K3_STEP(b0, b2, 65, B, A, 64)

  #pragma unroll
  for (int itl = 0; itl < 2; ++itl)
    #pragma unroll
    for (int ct = 0; ct < 4; ++ct)
      #pragma unroll
      for (int reg = 0; reg < 4; ++reg){
        int gi = gi0 + itl * 16 + q * 4 + reg;
        accA[((size_t)js * N + gi) * TC + head * PCH + ct * 16 + m] = acc[itl][ct][reg];
      }
  {
    float v0 = dsum0, v1 = dsum1;
    v0 += __shfl_xor(v0, 16); v0 += __shfl_xor(v0, 32);
    v1 += __shfl_xor(v1, 16); v1 += __shfl_xor(v1, 32);
    if (q == 0){
      accA[((size_t)js * N + row0)      * TC + head * PCH + 64] = v0;
      accA[((size_t)js * N + row0 + 16) * TC + head * PCH + 64] = v1;
    }
  }
}

// ---------------------------------------------------------------- k4: reduce partials -> xcat (lrelu 0.01)
__global__ void k4_redA(const float* __restrict__ accA, uint16_t* __restrict__ xcat){
  int i = blockIdx.x;
  int t = threadIdx.x;
  int k = t >> 6, cc = t & 63;
  size_t base = (size_t)i * TC + k * PCH;
  float v = 0.f, Z = 0.f;
  #pragma unroll
  for (int js = 0; js < 4; ++js){
    const float* p = accA + (size_t)js * N * TC + base;
    v += p[cc];
    Z += p[64];
  }
  float r = v / Z;
  xcat[(size_t)i * C1 + t] = f2b(lrelu(r, 0.01f));
}

// ---------------------------------------------------------------- k5: h2 = xcat@Wo, f1o/f2o (scaled), packed Bp2
__global__ __launch_bounds__(256) void k5_h2(const uint16_t* __restrict__ xcat,
    const float* __restrict__ Wo, const float* __restrict__ ao,
    uint16_t* __restrict__ Bp2, float* __restrict__ f1o, float* __restrict__ f2o)
{
  __shared__ uint16_t xs[16][256];
  __shared__ uint16_t hs[16][16];
  int t = threadIdx.x;
  int i0 = blockIdx.x * 16;
  #pragma unroll
  for (int r = 0; r < 2; ++r){
    int idx = t + 256 * r;
    int ii = idx >> 5, o4 = idx & 31;
    *(uint4*)&xs[ii][o4 * 8] = *(const uint4*)(xcat + (size_t)(i0 + ii) * C1 + o4 * 8);
  }
  __syncthreads();
  int ii = t >> 4, c = t & 15;
  float acc = 0.f;
  for (int f = 0; f < 256; ++f)
    acc += b2f(xs[ii][f]) * Wo[f * 16 + c];
  int i = i0 + ii;
  hs[ii][c] = f2b(acc);
  float u1 = acc * ao[c];
  float u2 = acc * ao[16 + c];
  #pragma unroll
  for (int off = 8; off; off >>= 1){
    u1 += __shfl_down(u1, off, 16);
    u2 += __shfl_down(u2, off, 16);
  }
  if (c == 0){ f1o[i] = u1 * LOG2E; f2o[i] = u2 * LOG2E; }
  __syncthreads();
  if (t < 32){
    int q_l = t >> 4, mm = t & 15;
    uint16_t tmp[8];
    #pragma unroll
    for (int s = 0; s < 8; ++s) tmp[s] = hs[8 * q_l + s][mm];
    int jcg = i0 >> 5, half = (i0 >> 4) & 1;
    size_t off = ((size_t)jcg * 64 + (2 * half + q_l) * 16 + mm) * 8;
    *(uint4*)(Bp2 + off) = *(uint4*)tmp;
  }
}

// ---------------------------------------------------------------- k6: phase-B attention — barrier-free, adjT, packed-B
#define K6_BODY(JC, CUR, NXT)                                                   \
  {                                                                             \
    const int jcn = ((JC) + 1) & 31;                                            \
    b##NXT = *(const bf16x8*)(bp2 + (size_t)jcn * 512);                         \
    w##NXT = adjT[(size_t)(js * 32 + jcn) * N + row];                           \
    f##NXT##0 = *(const float4*)(f2o + js * 1024 + jcn * 32 + 8 * q);           \
    f##NXT##1 = *(const float4*)(f2o + js * 1024 + jcn * 32 + 8 * q + 4);       \
    bf16x8 af = mk_frag(f1v, f##CUR##0, f##CUR##1,                              \
                        (w##CUR >> (8 * q)) & 255u, dsum);                      \
    acc0 = MFMA16(af, b##CUR, acc0);                                            \
  }

__global__ __launch_bounds__(256, 4) void k6_attB(const uint32_t* __restrict__ adjT,
    const uint16_t* __restrict__ Bp2, const float* __restrict__ f1o,
    const float* __restrict__ f2o, float* __restrict__ accB)
{
  const int t = threadIdx.x;
  const int ibl = blockIdx.x & 127;   // 128 i-tiles of 64 rows
  const int js  = blockIdx.x >> 7;    // 0..7
  const int gi0 = ibl * 64;

  const int lane = t & 63;
  const int w = t >> 6;               // wave 0..3
  const int m = lane & 15;
  const int q = lane >> 4;

  const int row = gi0 + w * 16 + m;
  const float f1v = f1o[row];
  const uint16_t* bp2 = Bp2 + ((size_t)js * 32 * 64) * 8 + lane * 8;

  f32x4 acc0 = {0.f, 0.f, 0.f, 0.f};
  float dsum = 0.f;

  bf16x8 bA, bB;
  uint32_t wA, wB;
  float4 fA0, fA1, fB0, fB1;

  {   // prologue: jc = 0
    bA = *(const bf16x8*)(bp2);
    wA = adjT[(size_t)(js * 32) * N + row];
    fA0 = *(const float4*)(f2o + js * 1024 + 8 * q);
    fA1 = *(const float4*)(f2o + js * 1024 + 8 * q + 4);
  }

  for (int jc = 0; jc < 32; jc += 2){
    K6_BODY(jc,     A, B)
    K6_BODY(jc + 1, B, A)
  }

  #pragma unroll
  for (int reg = 0; reg < 4; ++reg){
    int gi = gi0 + w * 16 + q * 4 + reg;
    accB[((size_t)js * N + gi) * C2 + m] = acc0[reg];
  }
  {
    float v = dsum;
    v += __shfl_xor(v, 16); v += __shfl_xor(v, 32);
    if (q == 0)
      accB[((size_t)js * N + row) * C2 + 16] = v;
  }
}

// ---------------------------------------------------------------- k7: reduce -> out (fp32)
__global__ void k7_redB(const float* __restrict__ accB, float* __restrict__ out){
  int idx = blockIdx.x * 256 + threadIdx.x;   // 131072
  int i = idx >> 4, c = idx & 15;
  float v = 0.f, Z = 0.f;
  #pragma unroll
  for (int js = 0; js < 8; ++js){
    const float* p = accB + ((size_t)js * N + i) * C2;
    v += p[c];
    Z += p[16];
  }
  out[idx] = v / Z;
}

// ================================================================ launch
extern "C" void kernel_launch(void* const* d_in, const int* in_sizes, int n_in,
                              void* d_out, int out_size, void* d_ws, size_t ws_size,
                              hipStream_t stream)
{
  const float* x   = (const float*)d_in[0];
  const int*   adj = (const int*)d_in[1];
  const float* Wh  = (const float*)d_in[2];
  const float* ah  = (const float*)d_in[3];
  const float* Wo  = (const float*)d_in[4];
  const float* ao  = (const float*)d_in[5];
  float* out = (float*)d_out;

  char* ws = (char*)d_ws;
  uint16_t* H    = (uint16_t*)(ws);                 // 4 MB    [8192][256] bf16
  uint16_t* Bp   = (uint16_t*)(ws + 4194304);       // 4 MB    packed B-fragments phase A
  float*    f1   = (float*)   (ws + 8388608);       // 128 KB  (pre-scaled by log2e)
  float*    f2   = (float*)   (ws + 8519680);       // 128 KB
  float*    accA = (float*)   (ws + 8650752);       // 34.08 MB [4][8192][260]
  uint16_t* xcat = (uint16_t*)(ws + 42729472);      // 4 MB    [8192][256] bf16
  uint16_t* Bp2  = (uint16_t*)(ws + 46923776);      // 256 KB  packed B-fragments phase B
  float*    f1o  = (float*)   (ws + 47185920);      // 32 KB
  float*    f2o  = (float*)   (ws + 47218688);      // 32 KB
  float*    accB = (float*)   (ws + 47251456);      // 8 MB    [8][8192][32]
  uint32_t* adjT = (uint32_t*)(ws + 55640064);      // 8 MB    transposed bitmask [256][8192] (end 64028672)

  hipLaunchKernelGGL(kp_pack,  dim3(16384), dim3(256), 0, stream, adj, adjT);
  hipLaunchKernelGGL(k1_h,     dim3(1024),  dim3(256), 0, stream, x, Wh, ah, H, f1, f2);
  hipLaunchKernelGGL(k2a_pack, dim3(512),   dim3(256), 0, stream, H, Bp);
  hipLaunchKernelGGL(k3_attA,  dim3(1024),  dim3(256), 0, stream, adjT, Bp, f1, f2, accA);
  hipLaunchKernelGGL(k4_redA,  dim3(8192),  dim3(256), 0, stream, accA, xcat);
  hipLaunchKernelGGL(k5_h2,    dim3(512),   dim3(256), 0, stream, xcat, Wo, ao, Bp2, f1o, f2o);
  hipLaunchKernelGGL(k6_attB,  dim3(1024),  dim3(256), 0, stream, adjT, Bp2, f1o, f2o, accB);
  hipLaunchKernelGGL(k7_redB,  dim3(512),   dim3(256), 0, stream, accB, out);
}

// Round 7
// 636.077 us; speedup vs baseline: 1.6123x; 1.0903x over previous
//
#include <hip/hip_runtime.h>
#include <stdint.h>

#define N      8192
#define FEAT   512
#define HID    64
#define NH     4
#define C1     256          // NH*HID
#define NCLS   16
#define IPB    8            // rows per block in k1
#define LOG2E  1.44269504f

typedef __attribute__((ext_vector_type(8))) short bf16x8;
typedef __attribute__((ext_vector_type(4))) float f32x4;

__device__ __forceinline__ float b2f(uint16_t u){
  uint32_t x = ((uint32_t)u) << 16;
  return __builtin_bit_cast(float, x);
}
__device__ __forceinline__ uint16_t f2b(float f){
  uint32_t x = __builtin_bit_cast(uint32_t, f);
  uint32_t r = (x + 0x7fffu + ((x >> 16) & 1u)) >> 16;
  return (uint16_t)r;
}
__device__ __forceinline__ float lrelu(float v, float a){ return fmaxf(v, a * v); }
__device__ __forceinline__ float fexp2(float x){
#if __has_builtin(__builtin_amdgcn_exp2f)
  return __builtin_amdgcn_exp2f(x);
#else
  return exp2f(x);
#endif
}
__device__ __forceinline__ uint32_t pk_bf16(float lo, float hi){
  uint32_t r;
  asm("v_cvt_pk_bf16_f32 %0, %1, %2" : "=v"(r) : "v"(lo), "v"(hi));
  return r;
}

// build one A-fragment (8 scores) fully in registers; masked by 8 adjacency bits
__device__ __forceinline__ bf16x8 mk_frag(float f1v, float4 fa, float4 fb,
                                          uint32_t ub, float& dsum){
  float e0, e1, e2, e3, e4, e5, e6, e7, s;
  s = f1v + fa.x; e0 = fexp2(fmaxf(s, 0.2f * s)); if (!(ub &   1u)) e0 = 0.f;
  s = f1v + fa.y; e1 = fexp2(fmaxf(s, 0.2f * s)); if (!(ub &   2u)) e1 = 0.f;
  s = f1v + fa.z; e2 = fexp2(fmaxf(s, 0.2f * s)); if (!(ub &   4u)) e2 = 0.f;
  s = f1v + fa.w; e3 = fexp2(fmaxf(s, 0.2f * s)); if (!(ub &   8u)) e3 = 0.f;
  s = f1v + fb.x; e4 = fexp2(fmaxf(s, 0.2f * s)); if (!(ub &  16u)) e4 = 0.f;
  s = f1v + fb.y; e5 = fexp2(fmaxf(s, 0.2f * s)); if (!(ub &  32u)) e5 = 0.f;
  s = f1v + fb.z; e6 = fexp2(fmaxf(s, 0.2f * s)); if (!(ub &  64u)) e6 = 0.f;
  s = f1v + fb.w; e7 = fexp2(fmaxf(s, 0.2f * s)); if (!(ub & 128u)) e7 = 0.f;
  dsum += ((e0 + e1) + (e2 + e3)) + ((e4 + e5) + (e6 + e7));
  union { uint32_t u[4]; bf16x8 v; } r;
  r.u[0] = pk_bf16(e0, e1);
  r.u[1] = pk_bf16(e2, e3);
  r.u[2] = pk_bf16(e4, e5);
  r.u[3] = pk_bf16(e6, e7);
  return r.v;
}

#define MFMA16(a, b, c) __builtin_amdgcn_mfma_f32_16x16x32_bf16((a), (b), (c), 0, 0, 0)

// ---------------------------------------------------------------- kp: adj -> transposed bitmask adjT[w32][row]
__global__ __launch_bounds__(256) void kp_pack(const int* __restrict__ adj,
                                               uint32_t* __restrict__ adjT){
  __shared__ uint32_t tile[2][64];
  int t = threadIdx.x, lane = t & 63, wv = t >> 6;
  int jt = blockIdx.x & 127;           // j-tile (64 cols)
  int i0 = (blockIdx.x >> 7) * 64;     // i-tile (64 rows)
  const int j0 = jt * 64;
  #pragma unroll
  for (int r = 0; r < 16; ++r){
    int row = wv * 16 + r;
    unsigned long long mb = __ballot(adj[(size_t)(i0 + row) * N + j0 + lane] > 0);
    if (lane == 0){
      tile[0][row] = (uint32_t)mb;
      tile[1][row] = (uint32_t)(mb >> 32);
    }
  }
  __syncthreads();
  if (t < 128){
    int ww = t >> 6, r = t & 63;
    adjT[(size_t)(jt * 2 + ww) * N + i0 + r] = tile[ww][r];
  }
}

// ---------------------------------------------------------------- k1: H = x @ Wh (scalar-x, coalesced W, no LDS)
__global__ __launch_bounds__(256) void k1_h(const float* __restrict__ x,
    const float* __restrict__ Wh, const float* __restrict__ ah,
    uint16_t* __restrict__ H, float* __restrict__ f1, float* __restrict__ f2)
{
  int t = threadIdx.x;
  int i0 = blockIdx.x * IPB;
  int k = t >> 6, cc = t & 63;
  const float* wcol = Wh + k * 32768 + cc;    // [k][f][cc], stride 64 over f
  float acc[IPB] = {};
  for (int f = 0; f < FEAT; f += 4){
    float w0 = wcol[(f + 0) * 64];
    float w1 = wcol[(f + 1) * 64];
    float w2 = wcol[(f + 2) * 64];
    float w3 = wcol[(f + 3) * 64];
    #pragma unroll
    for (int ii = 0; ii < IPB; ++ii){
      const float* xr = x + (size_t)(i0 + ii) * FEAT + f;   // wave-uniform -> s_load
      acc[ii] += xr[0] * w0 + xr[1] * w1 + xr[2] * w2 + xr[3] * w3;
    }
  }
  float a1 = ah[k * 128 + cc], a2 = ah[k * 128 + 64 + cc];
  #pragma unroll
  for (int ii = 0; ii < IPB; ++ii){
    int i = i0 + ii;
    H[(size_t)i * C1 + t] = f2b(acc[ii]);
    float c1v = acc[ii] * a1, c2v = acc[ii] * a2;
    #pragma unroll
    for (int off = 32; off; off >>= 1){
      c1v += __shfl_down(c1v, off);
      c2v += __shfl_down(c2v, off);
    }
    if (cc == 0){ f1[k * N + i] = c1v * LOG2E; f2[k * N + i] = c2v * LOG2E; }
  }
}

// ---------------------------------------------------------------- k2a: H -> fragment-packed Bp[head][jcg][ct][lane][8]
__global__ void k2a_pack(const uint16_t* __restrict__ H, uint16_t* __restrict__ Bp){
  __shared__ uint16_t tile[64][72];
  int bid = blockIdx.x;               // 128 i-tiles x 4 heads
  int k = bid & 3, it = bid >> 2;
  int i0 = it * 64;
  int t = threadIdx.x;
  #pragma unroll
  for (int r = 0; r < 4; ++r){
    int ii = r * 16 + (t >> 4);
    int pp = (t & 15) * 4;
    uint2 v = *(const uint2*)(H + (size_t)(i0 + ii) * C1 + k * 64 + pp);
    const uint16_t* s = (const uint16_t*)&v;
    tile[pp + 0][ii] = s[0]; tile[pp + 1][ii] = s[1];
    tile[pp + 2][ii] = s[2]; tile[pp + 3][ii] = s[3];
  }
  __syncthreads();
  #pragma unroll
  for (int r = 0; r < 2; ++r){
    int jl = r;
    int ct = t >> 6;
    int lane = t & 63;
    int m = lane & 15, q = lane >> 4;
    uint4 v = *(const uint4*)&tile[ct * 16 + m][jl * 32 + q * 8];
    size_t off = ((((size_t)k * 256 + (i0 >> 5) + jl) * 4 + ct) * 64 + lane) * 8;
    *(uint4*)(Bp + off) = v;
  }
}

// ---------------------------------------------------------------- k3: phase-A attention — LDS-fused j-reduction, 32 waves/CU
// block = 1024 thr = 16 waves = 4 heads x 4 j-quarters; i-tile = 16 rows; grid 512 (2 blocks/CU)
__global__ __launch_bounds__(1024, 8) void k3_attA(const uint32_t* __restrict__ adjT,
    const uint16_t* __restrict__ Bp, const float* __restrict__ f1,
    const float* __restrict__ f2, uint16_t* __restrict__ xcat)
{
  __shared__ float red[3][4][64][17];   // [jq-1][head][lane][ct*4+reg] (pad 17) ~52 KB
  __shared__ float zred[4][4][16];      // [jq][head][m]
  __shared__ float zfin[4][16];         // [head][row]

  const int t = threadIdx.x;
  const int gi0 = blockIdx.x * 16;      // 512 i-tiles
  const int lane = t & 63;
  const int wv = t >> 6;                // 0..15
  const int head = wv & 3;
  const int jq = wv >> 2;               // 0..3 (2048 j each)
  const int m = lane & 15;
  const int q = lane >> 4;

  const float* f2js = f2 + (size_t)head * N + jq * 2048;
  const float f1v = f1[(size_t)head * N + gi0 + m];
  const uint16_t* bpbase = Bp + (((size_t)head * 256 + jq * 64) * 4) * 512 + (size_t)lane * 8;
  const uint32_t* aw = adjT + (size_t)(jq * 64) * N + gi0 + m;

  f32x4 acc[4] = {};
  float dsum = 0.f;

  for (int jc = 0; jc < 64; ++jc){
    bf16x8 b[4];
    #pragma unroll
    for (int ct = 0; ct < 4; ++ct)
      b[ct] = *(const bf16x8*)(bpbase + (size_t)(jc * 4 + ct) * 512);
    uint32_t wb = aw[(size_t)jc * N];
    float4 fa = *(const float4*)(f2js + jc * 32 + 8 * q);
    float4 fb = *(const float4*)(f2js + jc * 32 + 8 * q + 4);
    bf16x8 af = mk_frag(f1v, fa, fb, (wb >> (8 * q)) & 255u, dsum);
    #pragma unroll
    for (int ct = 0; ct < 4; ++ct)
      acc[ct] = MFMA16(af, b[ct], acc[ct]);
  }

  // Z partial: reduce over q (lanes differ in bits 4..5), leave per-row at q==0
  dsum += __shfl_xor(dsum, 16);
  dsum += __shfl_xor(dsum, 32);
  if (q == 0) zred[jq][head][m] = dsum;
  if (jq != 0){
    #pragma unroll
    for (int ct = 0; ct < 4; ++ct)
      #pragma unroll
      for (int reg = 0; reg < 4; ++reg)
        red[jq - 1][head][lane][ct * 4 + reg] = acc[ct][reg];
  }
  __syncthreads();
  if (t < 64){
    int h = t >> 4, r = t & 15;
    zfin[h][r] = ((zred[0][h][r] + zred[1][h][r]) + (zred[2][h][r] + zred[3][h][r]));
  }
  __syncthreads();
  if (jq == 0){
    float zv[4];
    #pragma unroll
    for (int reg = 0; reg < 4; ++reg) zv[reg] = zfin[head][q * 4 + reg];
    #pragma unroll
    for (int ct = 0; ct < 4; ++ct)
      #pragma unroll
      for (int reg = 0; reg < 4; ++reg){
        float v = acc[ct][reg] + red[0][head][lane][ct * 4 + reg]
                + red[1][head][lane][ct * 4 + reg] + red[2][head][lane][ct * 4 + reg];
        float r2 = v / zv[reg];
        xcat[(size_t)(gi0 + q * 4 + reg) * C1 + head * 64 + ct * 16 + m] = f2b(lrelu(r2, 0.01f));
      }
  }
}

// ---------------------------------------------------------------- k5: h2 = xcat@Wo, f1o/f2o (scaled), packed Bp2
__global__ __launch_bounds__(256) void k5_h2(const uint16_t* __restrict__ xcat,
    const float* __restrict__ Wo, const float* __restrict__ ao,
    uint16_t* __restrict__ Bp2, float* __restrict__ f1o, float* __restrict__ f2o)
{
  __shared__ uint16_t xs[16][256];
  __shared__ uint16_t hs[16][16];
  int t = threadIdx.x;
  int i0 = blockIdx.x * 16;
  #pragma unroll
  for (int r = 0; r < 2; ++r){
    int idx = t + 256 * r;
    int ii = idx >> 5, o4 = idx & 31;
    *(uint4*)&xs[ii][o4 * 8] = *(const uint4*)(xcat + (size_t)(i0 + ii) * C1 + o4 * 8);
  }
  __syncthreads();
  int ii = t >> 4, c = t & 15;
  float acc = 0.f;
  for (int f = 0; f < 256; ++f)
    acc += b2f(xs[ii][f]) * Wo[f * 16 + c];
  int i = i0 + ii;
  hs[ii][c] = f2b(acc);
  float u1 = acc * ao[c];
  float u2 = acc * ao[16 + c];
  #pragma unroll
  for (int off = 8; off; off >>= 1){
    u1 += __shfl_down(u1, off, 16);
    u2 += __shfl_down(u2, off, 16);
  }
  if (c == 0){ f1o[i] = u1 * LOG2E; f2o[i] = u2 * LOG2E; }
  __syncthreads();
  if (t < 32){
    int q_l = t >> 4, mm = t & 15;
    uint16_t tmp[8];
    #pragma unroll
    for (int s = 0; s < 8; ++s) tmp[s] = hs[8 * q_l + s][mm];
    int jcg = i0 >> 5, half = (i0 >> 4) & 1;
    size_t off = ((size_t)jcg * 64 + (2 * half + q_l) * 16 + mm) * 8;
    *(uint4*)(Bp2 + off) = *(uint4*)tmp;
  }
}

// ---------------------------------------------------------------- k6: phase-B attention — LDS-fused, writes out directly
// block = 1024 thr = 16 waves = 16 j-slices (512 j each); i-tile = 16 rows; grid 512
__global__ __launch_bounds__(1024, 8) void k6_attB(const uint32_t* __restrict__ adjT,
    const uint16_t* __restrict__ Bp2, const float* __restrict__ f1o,
    const float* __restrict__ f2o, float* __restrict__ out)
{
  __shared__ float red[15][64][5];      // [wv-1][lane][reg] (pad 5) ~19 KB
  __shared__ float zredB[16][16];       // [wv][m]

  const int t = threadIdx.x;
  const int gi0 = blockIdx.x * 16;      // 512 i-tiles
  const int lane = t & 63;
  const int wv = t >> 6;                // j-slice 0..15
  const int m = lane & 15;
  const int q = lane >> 4;

  const float f1v = f1o[gi0 + m];
  const uint16_t* bp2 = Bp2 + (size_t)(wv * 16) * 512 + (size_t)lane * 8;
  const uint32_t* aw = adjT + (size_t)(wv * 16) * N + gi0 + m;
  const float* f2js = f2o + wv * 512;

  f32x4 acc = {0.f, 0.f, 0.f, 0.f};
  float dsum = 0.f;

  for (int jc = 0; jc < 16; ++jc){
    bf16x8 b = *(const bf16x8*)(bp2 + (size_t)jc * 512);
    uint32_t wb = aw[(size_t)jc * N];
    float4 fa = *(const float4*)(f2js + jc * 32 + 8 * q);
    float4 fb = *(const float4*)(f2js + jc * 32 + 8 * q + 4);
    bf16x8 af = mk_frag(f1v, fa, fb, (wb >> (8 * q)) & 255u, dsum);
    acc = MFMA16(af, b, acc);
  }

  dsum += __shfl_xor(dsum, 16);
  dsum += __shfl_xor(dsum, 32);
  if (q == 0) zredB[wv][m] = dsum;
  if (wv != 0){
    #pragma unroll
    for (int reg = 0; reg < 4; ++reg) red[wv - 1][lane][reg] = acc[reg];
  }
  __syncthreads();
  if (wv == 0){
    float zv[4];
    #pragma unroll
    for (int reg = 0; reg < 4; ++reg){
      float z = 0.f;
      #pragma unroll
      for (int k2 = 0; k2 < 16; ++k2) z += zredB[k2][q * 4 + reg];
      zv[reg] = z;
    }
    #pragma unroll
    for (int reg = 0; reg < 4; ++reg){
      float v = acc[reg];
      #pragma unroll
      for (int k2 = 0; k2 < 15; ++k2) v += red[k2][lane][reg];
      out[(size_t)(gi0 + q * 4 + reg) * NCLS + m] = v / zv[reg];
    }
  }
}

// ================================================================ launch
extern "C" void kernel_launch(void* const* d_in, const int* in_sizes, int n_in,
                              void* d_out, int out_size, void* d_ws, size_t ws_size,
                              hipStream_t stream)
{
  const float* x   = (const float*)d_in[0];
  const int*   adj = (const int*)d_in[1];
  const float* Wh  = (const float*)d_in[2];
  const float* ah  = (const float*)d_in[3];
  const float* Wo  = (const float*)d_in[4];
  const float* ao  = (const float*)d_in[5];
  float* out = (float*)d_out;

  char* ws = (char*)d_ws;
  uint16_t* H    = (uint16_t*)(ws);                 // 4 MB    [8192][256] bf16
  uint16_t* Bp   = (uint16_t*)(ws + 4194304);       // 4 MB    packed B-fragments phase A
  float*    f1   = (float*)   (ws + 8388608);       // 128 KB  (pre-scaled by log2e)
  float*    f2   = (float*)   (ws + 8519680);       // 128 KB
  uint16_t* xcat = (uint16_t*)(ws + 8650752);       // 4 MB    [8192][256] bf16
  uint16_t* Bp2  = (uint16_t*)(ws + 12845056);      // 256 KB  packed B-fragments phase B
  float*    f1o  = (float*)   (ws + 13107200);      // 32 KB
  float*    f2o  = (float*)   (ws + 13139968);      // 32 KB
  uint32_t* adjT = (uint32_t*)(ws + 13172736);      // 8 MB    transposed bitmask [256][8192]

  hipLaunchKernelGGL(kp_pack,  dim3(16384), dim3(256),  0, stream, adj, adjT);
  hipLaunchKernelGGL(k1_h,     dim3(1024),  dim3(256),  0, stream, x, Wh, ah, H, f1, f2);
  hipLaunchKernelGGL(k2a_pack, dim3(512),   dim3(256),  0, stream, H, Bp);
  hipLaunchKernelGGL(k3_attA,  dim3(512),   dim3(1024), 0, stream, adjT, Bp, f1, f2, xcat);
  hipLaunchKernelGGL(k5_h2,    dim3(512),   dim3(256),  0, stream, xcat, Wo, ao, Bp2, f1o, f2o);
  hipLaunchKernelGGL(k6_attB,  dim3(512),   dim3(1024), 0, stream, adjT, Bp2, f1o, f2o, out);
}

// Round 8
// 622.497 us; speedup vs baseline: 1.6474x; 1.0218x over previous
//
#include <hip/hip_runtime.h>
#include <stdint.h>

#define N      8192
#define FEAT   512
#define HID    64
#define NH     4
#define C1     256          // NH*HID
#define NCLS   16
#define IPB    8            // rows per block in k1
#define LOG2E  1.44269504f

typedef __attribute__((ext_vector_type(8))) short bf16x8;
typedef __attribute__((ext_vector_type(4))) float f32x4;

__device__ __forceinline__ float b2f(uint16_t u){
  uint32_t x = ((uint32_t)u) << 16;
  return __builtin_bit_cast(float, x);
}
__device__ __forceinline__ uint16_t f2b(float f){
  uint32_t x = __builtin_bit_cast(uint32_t, f);
  uint32_t r = (x + 0x7fffu + ((x >> 16) & 1u)) >> 16;
  return (uint16_t)r;
}
__device__ __forceinline__ float lrelu(float v, float a){ return fmaxf(v, a * v); }
__device__ __forceinline__ float fexp2(float x){
#if __has_builtin(__builtin_amdgcn_exp2f)
  return __builtin_amdgcn_exp2f(x);
#else
  return exp2f(x);
#endif
}
__device__ __forceinline__ uint32_t pk_bf16(float lo, float hi){
  uint32_t r;
  asm("v_cvt_pk_bf16_f32 %0, %1, %2" : "=v"(r) : "v"(lo), "v"(hi));
  return r;
}

// build one A-fragment (8 scores) fully in registers; masked by 8 adjacency bits
__device__ __forceinline__ bf16x8 mk_frag(float f1v, float4 fa, float4 fb,
                                          uint32_t ub, float& dsum){
  float e0, e1, e2, e3, e4, e5, e6, e7, s;
  s = f1v + fa.x; e0 = fexp2(fmaxf(s, 0.2f * s)); if (!(ub &   1u)) e0 = 0.f;
  s = f1v + fa.y; e1 = fexp2(fmaxf(s, 0.2f * s)); if (!(ub &   2u)) e1 = 0.f;
  s = f1v + fa.z; e2 = fexp2(fmaxf(s, 0.2f * s)); if (!(ub &   4u)) e2 = 0.f;
  s = f1v + fa.w; e3 = fexp2(fmaxf(s, 0.2f * s)); if (!(ub &   8u)) e3 = 0.f;
  s = f1v + fb.x; e4 = fexp2(fmaxf(s, 0.2f * s)); if (!(ub &  16u)) e4 = 0.f;
  s = f1v + fb.y; e5 = fexp2(fmaxf(s, 0.2f * s)); if (!(ub &  32u)) e5 = 0.f;
  s = f1v + fb.z; e6 = fexp2(fmaxf(s, 0.2f * s)); if (!(ub &  64u)) e6 = 0.f;
  s = f1v + fb.w; e7 = fexp2(fmaxf(s, 0.2f * s)); if (!(ub & 128u)) e7 = 0.f;
  dsum += ((e0 + e1) + (e2 + e3)) + ((e4 + e5) + (e6 + e7));
  union { uint32_t u[4]; bf16x8 v; } r;
  r.u[0] = pk_bf16(e0, e1);
  r.u[1] = pk_bf16(e2, e3);
  r.u[2] = pk_bf16(e4, e5);
  r.u[3] = pk_bf16(e6, e7);
  return r.v;
}

#define MFMA16(a, b, c) __builtin_amdgcn_mfma_f32_16x16x32_bf16((a), (b), (c), 0, 0, 0)

// ---------------------------------------------------------------- kp: adj -> transposed bitmask adjT[w32][row]
__global__ __launch_bounds__(256) void kp_pack(const int* __restrict__ adj,
                                               uint32_t* __restrict__ adjT){
  __shared__ uint32_t tile[2][64];
  int t = threadIdx.x, lane = t & 63, wv = t >> 6;
  int jt = blockIdx.x & 127;           // j-tile (64 cols)
  int i0 = (blockIdx.x >> 7) * 64;     // i-tile (64 rows)
  const int j0 = jt * 64;
  #pragma unroll
  for (int r = 0; r < 16; ++r){
    int row = wv * 16 + r;
    unsigned long long mb = __ballot(adj[(size_t)(i0 + row) * N + j0 + lane] > 0);
    if (lane == 0){
      tile[0][row] = (uint32_t)mb;
      tile[1][row] = (uint32_t)(mb >> 32);
    }
  }
  __syncthreads();
  if (t < 128){
    int ww = t >> 6, r = t & 63;
    adjT[(size_t)(jt * 2 + ww) * N + i0 + r] = tile[ww][r];
  }
}

// ---------------------------------------------------------------- k1: H = x @ Wh (scalar-x, coalesced W, no LDS)
__global__ __launch_bounds__(256) void k1_h(const float* __restrict__ x,
    const float* __restrict__ Wh, const float* __restrict__ ah,
    uint16_t* __restrict__ H, float* __restrict__ f1, float* __restrict__ f2)
{
  int t = threadIdx.x;
  int i0 = blockIdx.x * IPB;
  int k = t >> 6, cc = t & 63;
  const float* wcol = Wh + k * 32768 + cc;    // [k][f][cc], stride 64 over f
  float acc[IPB] = {};
  for (int f = 0; f < FEAT; f += 4){
    float w0 = wcol[(f + 0) * 64];
    float w1 = wcol[(f + 1) * 64];
    float w2 = wcol[(f + 2) * 64];
    float w3 = wcol[(f + 3) * 64];
    #pragma unroll
    for (int ii = 0; ii < IPB; ++ii){
      const float* xr = x + (size_t)(i0 + ii) * FEAT + f;   // wave-uniform -> s_load
      acc[ii] += xr[0] * w0 + xr[1] * w1 + xr[2] * w2 + xr[3] * w3;
    }
  }
  float a1 = ah[k * 128 + cc], a2 = ah[k * 128 + 64 + cc];
  #pragma unroll
  for (int ii = 0; ii < IPB; ++ii){
    int i = i0 + ii;
    H[(size_t)i * C1 + t] = f2b(acc[ii]);
    float c1v = acc[ii] * a1, c2v = acc[ii] * a2;
    #pragma unroll
    for (int off = 32; off; off >>= 1){
      c1v += __shfl_down(c1v, off);
      c2v += __shfl_down(c2v, off);
    }
    if (cc == 0){ f1[k * N + i] = c1v * LOG2E; f2[k * N + i] = c2v * LOG2E; }
  }
}

// ---------------------------------------------------------------- k2a: H -> fragment-packed Bp[head][jcg][ct][lane][8]
__global__ void k2a_pack(const uint16_t* __restrict__ H, uint16_t* __restrict__ Bp){
  __shared__ uint16_t tile[64][72];
  int bid = blockIdx.x;               // 128 i-tiles x 4 heads
  int k = bid & 3, it = bid >> 2;
  int i0 = it * 64;
  int t = threadIdx.x;
  #pragma unroll
  for (int r = 0; r < 4; ++r){
    int ii = r * 16 + (t >> 4);
    int pp = (t & 15) * 4;
    uint2 v = *(const uint2*)(H + (size_t)(i0 + ii) * C1 + k * 64 + pp);
    const uint16_t* s = (const uint16_t*)&v;
    tile[pp + 0][ii] = s[0]; tile[pp + 1][ii] = s[1];
    tile[pp + 2][ii] = s[2]; tile[pp + 3][ii] = s[3];
  }
  __syncthreads();
  #pragma unroll
  for (int r = 0; r < 2; ++r){
    int jl = r;
    int ct = t >> 6;
    int lane = t & 63;
    int m = lane & 15, q = lane >> 4;
    uint4 v = *(const uint4*)&tile[ct * 16 + m][jl * 32 + q * 8];
    size_t off = ((((size_t)k * 256 + (i0 >> 5) + jl) * 4 + ct) * 64 + lane) * 8;
    *(uint4*)(Bp + off) = v;
  }
}

// ---------------------------------------------------------------- k3: phase-A attention — fused reduce, 32-row tiles, no spill
// block = 512 thr = 8 waves = 2 heads x 4 j-quarters; i-tile = 32 rows; grid = 256 tiles x 2 head-pairs
#define K3_LOADB(BD, JC)                                                        \
  { const int jb = (JC) & 63;                                                   \
    _Pragma("unroll")                                                           \
    for (int ct = 0; ct < 4; ++ct)                                              \
      BD[ct] = *(const bf16x8*)(bpbase + (size_t)(jb * 4 + ct) * 512); }

#define K3_BODY(JC, CUR, NXT)                                                   \
  {                                                                             \
    K3_LOADB(b##NXT, (JC) + 1)                                                  \
    uint32_t wb0 = aw[(size_t)(JC) * N];                                        \
    uint32_t wb1 = aw[(size_t)(JC) * N + 16];                                   \
    float4 fa = *(const float4*)(f2js + (JC) * 32 + 8 * q);                     \
    float4 fb = *(const float4*)(f2js + (JC) * 32 + 8 * q + 4);                 \
    bf16x8 af0 = mk_frag(f1v0, fa, fb, (wb0 >> (8 * q)) & 255u, dsum0);         \
    bf16x8 af1 = mk_frag(f1v1, fa, fb, (wb1 >> (8 * q)) & 255u, dsum1);         \
    _Pragma("unroll")                                                           \
    for (int ct = 0; ct < 4; ++ct){                                             \
      acc[0][ct] = MFMA16(af0, b##CUR[ct], acc[0][ct]);                         \
      acc[1][ct] = MFMA16(af1, b##CUR[ct], acc[1][ct]);                         \
    }                                                                           \
  }

__global__ __launch_bounds__(512, 4) void k3_attA(const uint32_t* __restrict__ adjT,
    const uint16_t* __restrict__ Bp, const float* __restrict__ f1,
    const float* __restrict__ f2, uint16_t* __restrict__ xcat)
{
  __shared__ float red[3][2][64][33];   // [jq-1][hl][lane][itl*16+ct*4+reg], pad 33 -> 50.7 KB
  __shared__ float zred[4][2][2][16];   // [jq][hl][itl][m]
  __shared__ float zfin[2][2][16];      // [hl][itl][m]

  const int t = threadIdx.x;
  const int tile = blockIdx.x >> 1;     // 256 i-tiles of 32 rows
  const int hp   = blockIdx.x & 1;      // head pair
  const int gi0  = tile * 32;

  const int lane = t & 63;
  const int wv   = t >> 6;              // 0..7
  const int hl   = wv & 1;
  const int jq   = wv >> 1;             // 0..3 (2048 j each)
  const int head = hp * 2 + hl;
  const int m    = lane & 15;
  const int q    = lane >> 4;

  const float* f2js = f2 + (size_t)head * N + jq * 2048;
  const float f1v0 = f1[(size_t)head * N + gi0 + m];
  const float f1v1 = f1[(size_t)head * N + gi0 + 16 + m];
  const uint16_t* bpbase = Bp + ((size_t)(head * 256 + jq * 64) * 4) * 512 + (size_t)lane * 8;
  const uint32_t* aw = adjT + (size_t)(jq * 64) * N + gi0 + m;

  f32x4 acc[2][4] = {};
  float dsum0 = 0.f, dsum1 = 0.f;

  bf16x8 bA[4], bB[4];
  K3_LOADB(bA, 0)

  for (int jc = 0; jc < 64; jc += 2){
    K3_BODY(jc,     A, B)
    K3_BODY(jc + 1, B, A)
  }

  // Z partial: reduce over q (lanes differ in bits 4..5)
  dsum0 += __shfl_xor(dsum0, 16); dsum0 += __shfl_xor(dsum0, 32);
  dsum1 += __shfl_xor(dsum1, 16); dsum1 += __shfl_xor(dsum1, 32);
  if (q == 0){ zred[jq][hl][0][m] = dsum0; zred[jq][hl][1][m] = dsum1; }
  if (jq != 0){
    #pragma unroll
    for (int itl = 0; itl < 2; ++itl)
      #pragma unroll
      for (int ct = 0; ct < 4; ++ct)
        #pragma unroll
        for (int reg = 0; reg < 4; ++reg)
          red[jq - 1][hl][lane][itl * 16 + ct * 4 + reg] = acc[itl][ct][reg];
  }
  __syncthreads();
  if (t < 64){
    int h2 = t >> 5, itl2 = (t >> 4) & 1, mm = t & 15;
    zfin[h2][itl2][mm] = (zred[0][h2][itl2][mm] + zred[1][h2][itl2][mm])
                       + (zred[2][h2][itl2][mm] + zred[3][h2][itl2][mm]);
  }
  __syncthreads();
  if (jq == 0){
    #pragma unroll
    for (int itl = 0; itl < 2; ++itl){
      float zv[4];
      #pragma unroll
      for (int reg = 0; reg < 4; ++reg) zv[reg] = zfin[hl][itl][q * 4 + reg];
      #pragma unroll
      for (int ct = 0; ct < 4; ++ct)
        #pragma unroll
        for (int reg = 0; reg < 4; ++reg){
          float v = acc[itl][ct][reg]
                  + red[0][hl][lane][itl * 16 + ct * 4 + reg]
                  + red[1][hl][lane][itl * 16 + ct * 4 + reg]
                  + red[2][hl][lane][itl * 16 + ct * 4 + reg];
          float r2 = v / zv[reg];
          xcat[(size_t)(gi0 + itl * 16 + q * 4 + reg) * C1 + head * 64 + ct * 16 + m]
              = f2b(lrelu(r2, 0.01f));
        }
    }
  }
}

// ---------------------------------------------------------------- k5: h2 = xcat@Wo, f1o/f2o (scaled), packed Bp2
__global__ __launch_bounds__(256) void k5_h2(const uint16_t* __restrict__ xcat,
    const float* __restrict__ Wo, const float* __restrict__ ao,
    uint16_t* __restrict__ Bp2, float* __restrict__ f1o, float* __restrict__ f2o)
{
  __shared__ uint16_t xs[16][256];
  __shared__ uint16_t hs[16][16];
  int t = threadIdx.x;
  int i0 = blockIdx.x * 16;
  #pragma unroll
  for (int r = 0; r < 2; ++r){
    int idx = t + 256 * r;
    int ii = idx >> 5, o4 = idx & 31;
    *(uint4*)&xs[ii][o4 * 8] = *(const uint4*)(xcat + (size_t)(i0 + ii) * C1 + o4 * 8);
  }
  __syncthreads();
  int ii = t >> 4, c = t & 15;
  float acc = 0.f;
  for (int f = 0; f < 256; ++f)
    acc += b2f(xs[ii][f]) * Wo[f * 16 + c];
  int i = i0 + ii;
  hs[ii][c] = f2b(acc);
  float u1 = acc * ao[c];
  float u2 = acc * ao[16 + c];
  #pragma unroll
  for (int off = 8; off; off >>= 1){
    u1 += __shfl_down(u1, off, 16);
    u2 += __shfl_down(u2, off, 16);
  }
  if (c == 0){ f1o[i] = u1 * LOG2E; f2o[i] = u2 * LOG2E; }
  __syncthreads();
  if (t < 32){
    int q_l = t >> 4, mm = t & 15;
    uint16_t tmp[8];
    #pragma unroll
    for (int s = 0; s < 8; ++s) tmp[s] = hs[8 * q_l + s][mm];
    int jcg = i0 >> 5, half = (i0 >> 4) & 1;
    size_t off = ((size_t)jcg * 64 + (2 * half + q_l) * 16 + mm) * 8;
    *(uint4*)(Bp2 + off) = *(uint4*)tmp;
  }
}

// ---------------------------------------------------------------- k6: phase-B attention — fused reduce, 512 thr
// block = 512 thr = 8 waves = 8 j-slices (1024 j each); i-tile = 16 rows; grid 512
#define K6_BODY(JC, CUR, NXT)                                                   \
  {                                                                             \
    b##NXT = *(const bf16x8*)(bp2 + (size_t)(((JC) + 1) & 31) * 512);           \
    uint32_t wb = aw[(size_t)(JC) * N];                                         \
    float4 fa = *(const float4*)(f2js + (JC) * 32 + 8 * q);                     \
    float4 fb = *(const float4*)(f2js + (JC) * 32 + 8 * q + 4);                 \
    bf16x8 af = mk_frag(f1v, fa, fb, (wb >> (8 * q)) & 255u, dsum);             \
    acc = MFMA16(af, b##CUR, acc);                                              \
  }

__global__ __launch_bounds__(512, 4) void k6_attB(const uint32_t* __restrict__ adjT,
    const uint16_t* __restrict__ Bp2, const float* __restrict__ f1o,
    const float* __restrict__ f2o, float* __restrict__ out)
{
  __shared__ float red[7][64][5];      // [wv-1][lane][reg], pad 5 -> 8.75 KB
  __shared__ float zredB[8][16];       // [wv][m]

  const int t = threadIdx.x;
  const int gi0 = blockIdx.x * 16;     // 512 i-tiles
  const int lane = t & 63;
  const int wv = t >> 6;               // j-slice 0..7 (1024 j each)
  const int m = lane & 15;
  const int q = lane >> 4;

  const float f1v = f1o[gi0 + m];
  const uint16_t* bp2 = Bp2 + (size_t)(wv * 32) * 512 + (size_t)lane * 8;
  const uint32_t* aw = adjT + (size_t)(wv * 32) * N + gi0 + m;
  const float* f2js = f2o + wv * 1024;

  f32x4 acc = {0.f, 0.f, 0.f, 0.f};
  float dsum = 0.f;

  bf16x8 bA, bB;
  bA = *(const bf16x8*)(bp2);

  for (int jc = 0; jc < 32; jc += 2){
    K6_BODY(jc,     A, B)
    K6_BODY(jc + 1, B, A)
  }

  dsum += __shfl_xor(dsum, 16);
  dsum += __shfl_xor(dsum, 32);
  if (q == 0) zredB[wv][m] = dsum;
  if (wv != 0){
    #pragma unroll
    for (int reg = 0; reg < 4; ++reg) red[wv - 1][lane][reg] = acc[reg];
  }
  __syncthreads();
  if (wv == 0){
    #pragma unroll
    for (int reg = 0; reg < 4; ++reg){
      float z = 0.f;
      #pragma unroll
      for (int k2 = 0; k2 < 8; ++k2) z += zredB[k2][q * 4 + reg];
      float v = acc[reg];
      #pragma unroll
      for (int k2 = 0; k2 < 7; ++k2) v += red[k2][lane][reg];
      out[(size_t)(gi0 + q * 4 + reg) * NCLS + m] = v / z;
    }
  }
}

// ================================================================ launch
extern "C" void kernel_launch(void* const* d_in, const int* in_sizes, int n_in,
                              void* d_out, int out_size, void* d_ws, size_t ws_size,
                              hipStream_t stream)
{
  const float* x   = (const float*)d_in[0];
  const int*   adj = (const int*)d_in[1];
  const float* Wh  = (const float*)d_in[2];
  const float* ah  = (const float*)d_in[3];
  const float* Wo  = (const float*)d_in[4];
  const float* ao  = (const float*)d_in[5];
  float* out = (float*)d_out;

  char* ws = (char*)d_ws;
  uint16_t* H    = (uint16_t*)(ws);                 // 4 MB    [8192][256] bf16
  uint16_t* Bp   = (uint16_t*)(ws + 4194304);       // 4 MB    packed B-fragments phase A
  float*    f1   = (float*)   (ws + 8388608);       // 128 KB  (pre-scaled by log2e)
  float*    f2   = (float*)   (ws + 8519680);       // 128 KB
  uint16_t* xcat = (uint16_t*)(ws + 8650752);       // 4 MB    [8192][256] bf16
  uint16_t* Bp2  = (uint16_t*)(ws + 12845056);      // 256 KB  packed B-fragments phase B
  float*    f1o  = (float*)   (ws + 13107200);      // 32 KB
  float*    f2o  = (float*)   (ws + 13139968);      // 32 KB
  uint32_t* adjT = (uint32_t*)(ws + 13172736);      // 8 MB    transposed bitmask [256][8192]

  hipLaunchKernelGGL(kp_pack,  dim3(16384), dim3(256), 0, stream, adj, adjT);
  hipLaunchKernelGGL(k1_h,     dim3(1024),  dim3(256), 0, stream, x, Wh, ah, H, f1, f2);
  hipLaunchKernelGGL(k2a_pack, dim3(512),   dim3(256), 0, stream, H, Bp);
  hipLaunchKernelGGL(k3_attA,  dim3(512),   dim3(512), 0, stream, adjT, Bp, f1, f2, xcat);
  hipLaunchKernelGGL(k5_h2,    dim3(512),   dim3(256), 0, stream, xcat, Wo, ao, Bp2, f1o, f2o);
  hipLaunchKernelGGL(k6_attB,  dim3(512),   dim3(512), 0, stream, adjT, Bp2, f1o, f2o, out);
}

// Round 9
// 616.260 us; speedup vs baseline: 1.6641x; 1.0101x over previous
//
#include <hip/hip_runtime.h>
#include <stdint.h>

#define N      8192
#define FEAT   512
#define HID    64
#define NH     4
#define C1     256          // NH*HID
#define NCLS   16
#define IPB    8            // rows per block in k1
#define LOG2E  1.44269504f

typedef __attribute__((ext_vector_type(8))) short bf16x8;
typedef __attribute__((ext_vector_type(4))) float f32x4;

__device__ __forceinline__ float b2f(uint16_t u){
  uint32_t x = ((uint32_t)u) << 16;
  return __builtin_bit_cast(float, x);
}
__device__ __forceinline__ uint16_t f2b(float f){
  uint32_t x = __builtin_bit_cast(uint32_t, f);
  uint32_t r = (x + 0x7fffu + ((x >> 16) & 1u)) >> 16;
  return (uint16_t)r;
}
__device__ __forceinline__ float lrelu(float v, float a){ return fmaxf(v, a * v); }
__device__ __forceinline__ float fexp2(float x){
#if __has_builtin(__builtin_amdgcn_exp2f)
  return __builtin_amdgcn_exp2f(x);
#else
  return exp2f(x);
#endif
}
__device__ __forceinline__ uint32_t pk_bf16(float lo, float hi){
  uint32_t r;
  asm("v_cvt_pk_bf16_f32 %0, %1, %2" : "=v"(r) : "v"(lo), "v"(hi));
  return r;
}
// vcc-free mask: keep e iff bit k of ub set (k compile-time const)
__device__ __forceinline__ float andbit(float e, uint32_t ub, int k){
  uint32_t m = (uint32_t)(((int32_t)(ub << (31 - k))) >> 31);
  return __builtin_bit_cast(float, __builtin_bit_cast(uint32_t, e) & m);
}

// build one A-fragment (8 scores) in registers; mask via sign-spread AND (no vcc)
__device__ __forceinline__ bf16x8 mk_frag(float f1v, float4 fa, float4 fb, uint32_t ub){
  float e0, e1, e2, e3, e4, e5, e6, e7, s;
  s = f1v + fa.x; e0 = fexp2(fmaxf(s, 0.2f * s));
  s = f1v + fa.y; e1 = fexp2(fmaxf(s, 0.2f * s));
  s = f1v + fa.z; e2 = fexp2(fmaxf(s, 0.2f * s));
  s = f1v + fa.w; e3 = fexp2(fmaxf(s, 0.2f * s));
  s = f1v + fb.x; e4 = fexp2(fmaxf(s, 0.2f * s));
  s = f1v + fb.y; e5 = fexp2(fmaxf(s, 0.2f * s));
  s = f1v + fb.z; e6 = fexp2(fmaxf(s, 0.2f * s));
  s = f1v + fb.w; e7 = fexp2(fmaxf(s, 0.2f * s));
  e0 = andbit(e0, ub, 0); e1 = andbit(e1, ub, 1);
  e2 = andbit(e2, ub, 2); e3 = andbit(e3, ub, 3);
  e4 = andbit(e4, ub, 4); e5 = andbit(e5, ub, 5);
  e6 = andbit(e6, ub, 6); e7 = andbit(e7, ub, 7);
  union { uint32_t u[4]; bf16x8 v; } r;
  r.u[0] = pk_bf16(e0, e1);
  r.u[1] = pk_bf16(e2, e3);
  r.u[2] = pk_bf16(e4, e5);
  r.u[3] = pk_bf16(e6, e7);
  return r.v;
}

#define MFMA16(a, b, c) __builtin_amdgcn_mfma_f32_16x16x32_bf16((a), (b), (c), 0, 0, 0)

// ---------------------------------------------------------------- kp: adj -> transposed bitmask adjT[w32][row]
__global__ __launch_bounds__(256) void kp_pack(const int* __restrict__ adj,
                                               uint32_t* __restrict__ adjT){
  __shared__ uint32_t tile[2][64];
  int t = threadIdx.x, lane = t & 63, wv = t >> 6;
  int jt = blockIdx.x & 127;           // j-tile (64 cols)
  int i0 = (blockIdx.x >> 7) * 64;     // i-tile (64 rows)
  const int j0 = jt * 64;
  #pragma unroll
  for (int r = 0; r < 16; ++r){
    int row = wv * 16 + r;
    unsigned long long mb = __ballot(adj[(size_t)(i0 + row) * N + j0 + lane] > 0);
    if (lane == 0){
      tile[0][row] = (uint32_t)mb;
      tile[1][row] = (uint32_t)(mb >> 32);
    }
  }
  __syncthreads();
  if (t < 128){
    int ww = t >> 6, r = t & 63;
    adjT[(size_t)(jt * 2 + ww) * N + i0 + r] = tile[ww][r];
  }
}

// ---------------------------------------------------------------- k1: H = x @ Wh (w-prefetch, float4 uniform x)
__global__ __launch_bounds__(256) void k1_h(const float* __restrict__ x,
    const float* __restrict__ Wh, const float* __restrict__ ah,
    uint16_t* __restrict__ H, float* __restrict__ f1, float* __restrict__ f2)
{
  int t = threadIdx.x;
  int i0 = blockIdx.x * IPB;
  int k = t >> 6, cc = t & 63;
  const float* wcol = Wh + k * 32768 + cc;    // [k][f][cc], stride 64 over f
  float acc[IPB] = {};
  float w0 = wcol[0], w1 = wcol[64], w2 = wcol[128], w3 = wcol[192];
  for (int f = 0; f < FEAT; f += 4){
    int fn = (f + 4) & 511;                   // wrap; extra reload of f=0 is harmless
    float v0 = wcol[(fn + 0) * 64];
    float v1 = wcol[(fn + 1) * 64];
    float v2 = wcol[(fn + 2) * 64];
    float v3 = wcol[(fn + 3) * 64];
    #pragma unroll
    for (int ii = 0; ii < IPB; ++ii){
      float4 xv = *(const float4*)(x + (size_t)(i0 + ii) * FEAT + f);  // uniform -> s_load
      acc[ii] += xv.x * w0 + xv.y * w1 + xv.z * w2 + xv.w * w3;
    }
    w0 = v0; w1 = v1; w2 = v2; w3 = v3;
  }
  float a1 = ah[k * 128 + cc], a2 = ah[k * 128 + 64 + cc];
  #pragma unroll
  for (int ii = 0; ii < IPB; ++ii){
    int i = i0 + ii;
    H[(size_t)i * C1 + t] = f2b(acc[ii]);
    float c1v = acc[ii] * a1, c2v = acc[ii] * a2;
    #pragma unroll
    for (int off = 32; off; off >>= 1){
      c1v += __shfl_down(c1v, off);
      c2v += __shfl_down(c2v, off);
    }
    if (cc == 0){ f1[k * N + i] = c1v * LOG2E; f2[k * N + i] = c2v * LOG2E; }
  }
}

// ---------------------------------------------------------------- k2a: H -> fragment-packed Bp[head][jcg][ct][lane][8]
__global__ void k2a_pack(const uint16_t* __restrict__ H, uint16_t* __restrict__ Bp){
  __shared__ uint16_t tile[64][72];
  int bid = blockIdx.x;               // 128 i-tiles x 4 heads
  int k = bid & 3, it = bid >> 2;
  int i0 = it * 64;
  int t = threadIdx.x;
  #pragma unroll
  for (int r = 0; r < 4; ++r){
    int ii = r * 16 + (t >> 4);
    int pp = (t & 15) * 4;
    uint2 v = *(const uint2*)(H + (size_t)(i0 + ii) * C1 + k * 64 + pp);
    const uint16_t* s = (const uint16_t*)&v;
    tile[pp + 0][ii] = s[0]; tile[pp + 1][ii] = s[1];
    tile[pp + 2][ii] = s[2]; tile[pp + 3][ii] = s[3];
  }
  __syncthreads();
  #pragma unroll
  for (int r = 0; r < 2; ++r){
    int jl = r;
    int ct = t >> 6;
    int lane = t & 63;
    int m = lane & 15, q = lane >> 4;
    uint4 v = *(const uint4*)&tile[ct * 16 + m][jl * 32 + q * 8];
    size_t off = ((((size_t)k * 256 + (i0 >> 5) + jl) * 4 + ct) * 64 + lane) * 8;
    *(uint4*)(Bp + off) = v;
  }
}

// ---------------------------------------------------------------- k3: phase-A attention — wf-prefetch + Z-MFMA
#define K3_LOADWF(WD0, WD1, FAD, FBD, JC)                                       \
  { const int jw = (JC) & 63;                                                   \
    WD0 = aw[(size_t)jw * N];                                                   \
    WD1 = aw[(size_t)jw * N + 16];                                              \
    FAD = *(const float4*)(f2js + jw * 32 + 8 * q);                             \
    FBD = *(const float4*)(f2js + jw * 32 + 8 * q + 4); }

#define K3_BODY(JC, CUR, NXT)                                                   \
  {                                                                             \
    bf16x8 b[4];                                                                \
    _Pragma("unroll")                                                           \
    for (int ct = 0; ct < 4; ++ct)                                              \
      b[ct] = *(const bf16x8*)(bpbase + (size_t)(((JC) & 63) * 4 + ct) * 512);  \
    K3_LOADWF(w##NXT##0, w##NXT##1, f##NXT##a, f##NXT##b, (JC) + 1)             \
    uint32_t ub0 = (w##CUR##0 >> (8 * q)) & 255u;                               \
    uint32_t ub1 = (w##CUR##1 >> (8 * q)) & 255u;                               \
    bf16x8 af0 = mk_frag(f1v0, f##CUR##a, f##CUR##b, ub0);                      \
    bf16x8 af1 = mk_frag(f1v1, f##CUR##a, f##CUR##b, ub1);                      \
    accz0 = MFMA16(af0, bones, accz0);                                          \
    accz1 = MFMA16(af1, bones, accz1);                                          \
    _Pragma("unroll")                                                           \
    for (int ct = 0; ct < 4; ++ct){                                             \
      acc[0][ct] = MFMA16(af0, b[ct], acc[0][ct]);                              \
      acc[1][ct] = MFMA16(af1, b[ct], acc[1][ct]);                              \
    }                                                                           \
  }

__global__ __launch_bounds__(512, 4) void k3_attA(const uint32_t* __restrict__ adjT,
    const uint16_t* __restrict__ Bp, const float* __restrict__ f1,
    const float* __restrict__ f2, uint16_t* __restrict__ xcat)
{
  __shared__ float red[3][2][64][33];   // [jq-1][hl][lane][itl*16+ct*4+reg] ~50.7 KB
  __shared__ float zred[4][2][2][16];   // [jq][hl][itl][row]
  __shared__ float zfin[2][2][16];      // [hl][itl][row]

  const int t = threadIdx.x;
  const int tile = blockIdx.x >> 1;     // 256 i-tiles of 32 rows
  const int hp   = blockIdx.x & 1;      // head pair
  const int gi0  = tile * 32;

  const int lane = t & 63;
  const int wv   = t >> 6;              // 0..7
  const int hl   = wv & 1;
  const int jq   = wv >> 1;             // 0..3 (2048 j each)
  const int head = hp * 2 + hl;
  const int m    = lane & 15;
  const int q    = lane >> 4;

  const float* f2js = f2 + (size_t)head * N + jq * 2048;
  const float f1v0 = f1[(size_t)head * N + gi0 + m];
  const float f1v1 = f1[(size_t)head * N + gi0 + 16 + m];
  const uint16_t* bpbase = Bp + ((size_t)(head * 256 + jq * 64) * 4) * 512 + (size_t)lane * 8;
  const uint32_t* aw = adjT + (size_t)(jq * 64) * N + gi0 + m;

  // ones B-fragment: B[k][n] = (n==0) -> lanes with m==0 hold bf16(1.0)
  const uint16_t ow = (m == 0) ? 0x3F80 : 0;
  bf16x8 bones = { (short)ow, (short)ow, (short)ow, (short)ow,
                   (short)ow, (short)ow, (short)ow, (short)ow };

  f32x4 acc[2][4] = {};
  f32x4 accz0 = {0.f, 0.f, 0.f, 0.f}, accz1 = {0.f, 0.f, 0.f, 0.f};

  uint32_t wA0, wA1, wB0, wB1;
  float4 fAa, fAb, fBa, fBb;

  K3_LOADWF(wA0, wA1, fAa, fAb, 0)

  for (int jc = 0; jc < 64; jc += 2){
    K3_BODY(jc,     A, B)
    K3_BODY(jc + 1, B, A)
  }

  // Z rows: D[r][0] at lanes m==0, r = q*4+reg
  if (m == 0){
    #pragma unroll
    for (int reg = 0; reg < 4; ++reg){
      zred[jq][hl][0][q * 4 + reg] = accz0[reg];
      zred[jq][hl][1][q * 4 + reg] = accz1[reg];
    }
  }
  if (jq != 0){
    #pragma unroll
    for (int itl = 0; itl < 2; ++itl)
      #pragma unroll
      for (int ct = 0; ct < 4; ++ct)
        #pragma unroll
        for (int reg = 0; reg < 4; ++reg)
          red[jq - 1][hl][lane][itl * 16 + ct * 4 + reg] =
            (itl == 0) ? acc[0][ct][reg] : acc[1][ct][reg];
  }
  __syncthreads();
  if (t < 64){
    int h2 = t >> 5, itl2 = (t >> 4) & 1, mm = t & 15;
    zfin[h2][itl2][mm] = (zred[0][h2][itl2][mm] + zred[1][h2][itl2][mm])
                       + (zred[2][h2][itl2][mm] + zred[3][h2][itl2][mm]);
  }
  __syncthreads();
  if (jq == 0){
    #pragma unroll
    for (int itl = 0; itl < 2; ++itl){
      float zv[4];
      #pragma unroll
      for (int reg = 0; reg < 4; ++reg) zv[reg] = zfin[hl][itl][q * 4 + reg];
      #pragma unroll
      for (int ct = 0; ct < 4; ++ct)
        #pragma unroll
        for (int reg = 0; reg < 4; ++reg){
          float base = (itl == 0) ? acc[0][ct][reg] : acc[1][ct][reg];
          float v = base
                  + red[0][hl][lane][itl * 16 + ct * 4 + reg]
                  + red[1][hl][lane][itl * 16 + ct * 4 + reg]
                  + red[2][hl][lane][itl * 16 + ct * 4 + reg];
          float r2 = v / zv[reg];
          xcat[(size_t)(gi0 + itl * 16 + q * 4 + reg) * C1 + head * 64 + ct * 16 + m]
              = f2b(lrelu(r2, 0.01f));
        }
    }
  }
}

// ---------------------------------------------------------------- k5: h2 = xcat@Wo, f1o/f2o (scaled), packed Bp2
__global__ __launch_bounds__(256) void k5_h2(const uint16_t* __restrict__ xcat,
    const float* __restrict__ Wo, const float* __restrict__ ao,
    uint16_t* __restrict__ Bp2, float* __restrict__ f1o, float* __restrict__ f2o)
{
  __shared__ uint16_t xs[16][256];
  __shared__ uint16_t hs[16][16];
  int t = threadIdx.x;
  int i0 = blockIdx.x * 16;
  #pragma unroll
  for (int r = 0; r < 2; ++r){
    int idx = t + 256 * r;
    int ii = idx >> 5, o4 = idx & 31;
    *(uint4*)&xs[ii][o4 * 8] = *(const uint4*)(xcat + (size_t)(i0 + ii) * C1 + o4 * 8);
  }
  __syncthreads();
  int ii = t >> 4, c = t & 15;
  float acc = 0.f;
  for (int f = 0; f < 256; ++f)
    acc += b2f(xs[ii][f]) * Wo[f * 16 + c];
  int i = i0 + ii;
  hs[ii][c] = f2b(acc);
  float u1 = acc * ao[c];
  float u2 = acc * ao[16 + c];
  #pragma unroll
  for (int off = 8; off; off >>= 1){
    u1 += __shfl_down(u1, off, 16);
    u2 += __shfl_down(u2, off, 16);
  }
  if (c == 0){ f1o[i] = u1 * LOG2E; f2o[i] = u2 * LOG2E; }
  __syncthreads();
  if (t < 32){
    int q_l = t >> 4, mm = t & 15;
    uint16_t tmp[8];
    #pragma unroll
    for (int s = 0; s < 8; ++s) tmp[s] = hs[8 * q_l + s][mm];
    int jcg = i0 >> 5, half = (i0 >> 4) & 1;
    size_t off = ((size_t)jcg * 64 + (2 * half + q_l) * 16 + mm) * 8;
    *(uint4*)(Bp2 + off) = *(uint4*)tmp;
  }
}

// ---------------------------------------------------------------- k6: phase-B attention — wf-prefetch + Z-MFMA
#define K6_LOADWF(WD, FAD, FBD, JC)                                             \
  { const int jw = (JC) & 31;                                                   \
    WD = aw[(size_t)jw * N];                                                    \
    FAD = *(const float4*)(f2js + jw * 32 + 8 * q);                             \
    FBD = *(const float4*)(f2js + jw * 32 + 8 * q + 4); }

#define K6_BODY(JC, CUR, NXT)                                                   \
  {                                                                             \
    bf16x8 b = *(const bf16x8*)(bp2 + (size_t)((JC) & 31) * 512);               \
    K6_LOADWF(w##NXT, f##NXT##a, f##NXT##b, (JC) + 1)                           \
    uint32_t ub = (w##CUR >> (8 * q)) & 255u;                                   \
    bf16x8 af = mk_frag(f1v, f##CUR##a, f##CUR##b, ub);                         \
    accz = MFMA16(af, bones, accz);                                             \
    acc = MFMA16(af, b, acc);                                                   \
  }

__global__ __launch_bounds__(512, 4) void k6_attB(const uint32_t* __restrict__ adjT,
    const uint16_t* __restrict__ Bp2, const float* __restrict__ f1o,
    const float* __restrict__ f2o, float* __restrict__ out)
{
  __shared__ float red[7][64][5];      // [wv-1][lane][reg]
  __shared__ float zredB[8][16];       // [wv][row]

  const int t = threadIdx.x;
  const int gi0 = blockIdx.x * 16;     // 512 i-tiles
  const int lane = t & 63;
  const int wv = t >> 6;               // j-slice 0..7 (1024 j each)
  const int m = lane & 15;
  const int q = lane >> 4;

  const float f1v = f1o[gi0 + m];
  const uint16_t* bp2 = Bp2 + (size_t)(wv * 32) * 512 + (size_t)lane * 8;
  const uint32_t* aw = adjT + (size_t)(wv * 32) * N + gi0 + m;
  const float* f2js = f2o + wv * 1024;

  const uint16_t ow = (m == 0) ? 0x3F80 : 0;
  bf16x8 bones = { (short)ow, (short)ow, (short)ow, (short)ow,
                   (short)ow, (short)ow, (short)ow, (short)ow };

  f32x4 acc = {0.f, 0.f, 0.f, 0.f};
  f32x4 accz = {0.f, 0.f, 0.f, 0.f};

  uint32_t wA, wB;
  float4 fAa, fAb, fBa, fBb;

  K6_LOADWF(wA, fAa, fAb, 0)

  for (int jc = 0; jc < 32; jc += 2){
    K6_BODY(jc,     A, B)
    K6_BODY(jc + 1, B, A)
  }

  if (m == 0){
    #pragma unroll
    for (int reg = 0; reg < 4; ++reg) zredB[wv][q * 4 + reg] = accz[reg];
  }
  if (wv != 0){
    #pragma unroll
    for (int reg = 0; reg < 4; ++reg) red[wv - 1][lane][reg] = acc[reg];
  }
  __syncthreads();
  if (wv == 0){
    #pragma unroll
    for (int reg = 0; reg < 4; ++reg){
      float z = 0.f;
      #pragma unroll
      for (int k2 = 0; k2 < 8; ++k2) z += zredB[k2][q * 4 + reg];
      float v = acc[reg];
      #pragma unroll
      for (int k2 = 0; k2 < 7; ++k2) v += red[k2][lane][reg];
      out[(size_t)(gi0 + q * 4 + reg) * NCLS + m] = v / z;
    }
  }
}

// ================================================================ launch
extern "C" void kernel_launch(void* const* d_in, const int* in_sizes, int n_in,
                              void* d_out, int out_size, void* d_ws, size_t ws_size,
                              hipStream_t stream)
{
  const float* x   = (const float*)d_in[0];
  const int*   adj = (const int*)d_in[1];
  const float* Wh  = (const float*)d_in[2];
  const float* ah  = (const float*)d_in[3];
  const float* Wo  = (const float*)d_in[4];
  const float* ao  = (const float*)d_in[5];
  float* out = (float*)d_out;

  char* ws = (char*)d_ws;
  uint16_t* H    = (uint16_t*)(ws);                 // 4 MB    [8192][256] bf16
  uint16_t* Bp   = (uint16_t*)(ws + 4194304);       // 4 MB    packed B-fragments phase A
  float*    f1   = (float*)   (ws + 8388608);       // 128 KB  (pre-scaled by log2e)
  float*    f2   = (float*)   (ws + 8519680);       // 128 KB
  uint16_t* xcat = (uint16_t*)(ws + 8650752);       // 4 MB    [8192][256] bf16
  uint16_t* Bp2  = (uint16_t*)(ws + 12845056);      // 256 KB  packed B-fragments phase B
  float*    f1o  = (float*)   (ws + 13107200);      // 32 KB
  float*    f2o  = (float*)   (ws + 13139968);      // 32 KB
  uint32_t* adjT = (uint32_t*)(ws + 13172736);      // 8 MB    transposed bitmask [256][8192]

  hipLaunchKernelGGL(kp_pack,  dim3(16384), dim3(256), 0, stream, adj, adjT);
  hipLaunchKernelGGL(k1_h,     dim3(1024),  dim3(256), 0, stream, x, Wh, ah, H, f1, f2);
  hipLaunchKernelGGL(k2a_pack, dim3(512),   dim3(256), 0, stream, H, Bp);
  hipLaunchKernelGGL(k3_attA,  dim3(512),   dim3(512), 0, stream, adjT, Bp, f1, f2, xcat);
  hipLaunchKernelGGL(k5_h2,    dim3(512),   dim3(256), 0, stream, xcat, Wo, ao, Bp2, f1o, f2o);
  hipLaunchKernelGGL(k6_attB,  dim3(512),   dim3(512), 0, stream, adjT, Bp2, f1o, f2o, out);
}